// Round 4
// baseline (470.343 us; speedup 1.0000x reference)
//
#include <hip/hip_runtime.h>

#define BB 4
#define NN 1024
#define DD 256
#define NHEADS 8
#define NPTS 4
#define NKSAMP 10
#define HHF 200
#define WWF 200
#define HWF (HHF*WWF)
#define KTOT 2304   // 2048 (g) + 256 (qe residual via combined Wq@Wout)

typedef __attribute__((ext_vector_type(8))) short bf16x8;
typedef __attribute__((ext_vector_type(4))) float f32x4;

__device__ __forceinline__ unsigned short f2bf(float f){
    unsigned u = __float_as_uint(f);
    return (unsigned short)((u + 0x7FFFu + ((u >> 16) & 1u)) >> 16);
}
__device__ __forceinline__ void load_bf16x8(const unsigned short* p, float* v){
    int4 t = *reinterpret_cast<const int4*>(p);
    unsigned q0 = (unsigned)t.x, q1 = (unsigned)t.y, q2 = (unsigned)t.z, q3 = (unsigned)t.w;
    v[0] = __uint_as_float(q0 << 16); v[1] = __uint_as_float(q0 & 0xFFFF0000u);
    v[2] = __uint_as_float(q1 << 16); v[3] = __uint_as_float(q1 & 0xFFFF0000u);
    v[4] = __uint_as_float(q2 << 16); v[5] = __uint_as_float(q2 & 0xFFFF0000u);
    v[6] = __uint_as_float(q3 << 16); v[7] = __uint_as_float(q3 & 0xFFFF0000u);
}
__device__ __forceinline__ void store_bf16x8(unsigned short* p, const float* v){
    int4 t;
    t.x = (int)((unsigned)f2bf(v[0]) | ((unsigned)f2bf(v[1]) << 16));
    t.y = (int)((unsigned)f2bf(v[2]) | ((unsigned)f2bf(v[3]) << 16));
    t.z = (int)((unsigned)f2bf(v[4]) | ((unsigned)f2bf(v[5]) << 16));
    t.w = (int)((unsigned)f2bf(v[6]) | ((unsigned)f2bf(v[7]) << 16));
    *reinterpret_cast<int4*>(p) = t;
}

// ================== K1: front  (oa | prep | transpose) — round-1 (153 µs) form =====
// 64-KB static LDS (measured better than 34.8-KB variant: co-residency hurt the
// long-pole oa/prep blocks more than transpose occupancy helped).
// blocks [0,64)    : oa -- q = qe@Wq+bq (full-256k LDS stage), oa = q@[Woff|Wattn]+b
// blocks [64,113)  : prep -- WgT (combined back-end weights), Bh, bconst
// blocks [113,...) : transpose -- bev (B,C,HW) f32 -> bevT (B,HW,C) bf16, 64x64 tiles
__global__ __launch_bounds__(256) void front_kernel(
    const float* __restrict__ qe,   const float* __restrict__ ctrl,
    const float* __restrict__ pc,
    const float* __restrict__ Wq,   const float* __restrict__ bq,
    const float* __restrict__ Wval, const float* __restrict__ bval,
    const float* __restrict__ Woff, const float* __restrict__ boff,
    const float* __restrict__ Wattn,const float* __restrict__ battn,
    const float* __restrict__ Wdo,  const float* __restrict__ bdo,
    const float* __restrict__ Wout, const float* __restrict__ bout,
    const float* __restrict__ bev,
    unsigned short* __restrict__ bevT,
    unsigned short* __restrict__ WgT,
    float* __restrict__ Bh, float* __restrict__ bconst,
    float* __restrict__ coords, float* __restrict__ wsb)
{
    __shared__ __align__(16) char smem[65536];
    const int bx  = blockIdx.x;
    const int tid = threadIdx.x;

    if (bx < 64){
        // ---------------- oa role: 64 query rows ----------------
        const int m0 = bx * 64;
        float (*As)[64] = (float(*)[64])smem;       // qe^T [256 k][64 r], exactly 64KB
        __shared__ float cen_s[64][2];
        {
            int r  = tid >> 2;
            int kb = (tid & 3) * 4;
            #pragma unroll
            for (int kk = 0; kk < 16; kk++){
                int k = kb + kk*16;
                float4 v = *reinterpret_cast<const float4*>(qe + (size_t)(m0 + r)*256 + k);
                As[k+0][r] = v.x; As[k+1][r] = v.y; As[k+2][r] = v.z; As[k+3][r] = v.w;
            }
        }
        if (tid < 64){   // bezier centers (independent of As)
            int m = m0 + tid;
            float cx[4], cy[4];
            #pragma unroll
            for (int i = 0; i < 4; i++){
                cx[i] = ctrl[(size_t)m*8 + i*2 + 0];
                cy[i] = ctrl[(size_t)m*8 + i*2 + 1];
            }
            float lox = pc[0], loy = pc[1];
            float spx = pc[3] - lox, spy = pc[4] - loy;
            float sx = 0.f, sy = 0.f;
            for (int k = 0; k < NKSAMP; k++){
                float t = (float)k / (float)(NKSAMP - 1);
                float u = 1.f - t;
                float c0 = u*u*u, c1 = 3.f*u*u*t, c2 = 3.f*u*t*t, c3 = t*t*t;
                float dx = c0*cx[0] + c1*cx[1] + c2*cx[2] + c3*cx[3];
                float dy = c0*cy[0] + c1*cy[1] + c2*cy[2] + c3*cy[3];
                float rx = fminf(fmaxf((dx - lox)/spx, 0.01f), 0.99f);
                float ry = fminf(fmaxf((dy - loy)/spy, 0.01f), 0.99f);
                sx += rx; sy += ry;
            }
            cen_s[tid][0] = (sx / (float)NKSAMP) * (float)WWF - 0.5f;
            cen_s[tid][1] = (sy / (float)NKSAMP) * (float)HHF - 0.5f;
        }
        __syncthreads();
        const int ti = tid & 15;
        const int tj = tid >> 4;

        // phase B: q = qe@Wq + bq, held in regs as qreg[n-part][row i]
        float qreg[16][4];
        #pragma unroll
        for (int slab = 0; slab < 4; slab++){
            float acc[4][4];
            #pragma unroll
            for (int i = 0; i < 4; i++)
                #pragma unroll
                for (int j = 0; j < 4; j++) acc[i][j] = 0.f;
            #pragma unroll 4
            for (int c = 0; c < 256; c++){
                float4 a = *reinterpret_cast<const float4*>(&As[c][ti*4]);
                float av[4] = {a.x, a.y, a.z, a.w};
                float4 b = *reinterpret_cast<const float4*>(Wq + (size_t)c*256 + slab*64 + tj*4);
                float bv[4] = {b.x, b.y, b.z, b.w};
                #pragma unroll
                for (int i = 0; i < 4; i++)
                    #pragma unroll
                    for (int j = 0; j < 4; j++) acc[i][j] += av[i]*bv[j];
            }
            #pragma unroll
            for (int j = 0; j < 4; j++){
                float bqv = bq[slab*64 + tj*4 + j];
                #pragma unroll
                for (int i = 0; i < 4; i++) qreg[slab*4 + j][i] = acc[i][j] + bqv;
            }
        }
        __syncthreads();                 // As consumed
        float* qT = (float*)smem;        // q^T [256 n][64 r]
        #pragma unroll
        for (int t = 0; t < 16; t++){
            int n = (t >> 2)*64 + tj*4 + (t & 3);
            float4 v; v.x = qreg[t][0]; v.y = qreg[t][1]; v.z = qreg[t][2]; v.w = qreg[t][3];
            *reinterpret_cast<float4*>(&qT[(size_t)n*64 + ti*4]) = v;
        }
        __syncthreads();

        // phase C: oa = q @ [Woff|Wattn]
        float ao[4][4], aa[4][2];
        #pragma unroll
        for (int i = 0; i < 4; i++){
            #pragma unroll
            for (int j = 0; j < 4; j++) ao[i][j] = 0.f;
            aa[i][0] = 0.f; aa[i][1] = 0.f;
        }
        #pragma unroll 4
        for (int c = 0; c < 256; c++){
            float4 a = *reinterpret_cast<const float4*>(&qT[(size_t)c*64 + ti*4]);
            float av[4] = {a.x, a.y, a.z, a.w};
            float4 bo = *reinterpret_cast<const float4*>(Woff  + (size_t)c*64 + tj*4);
            float2 ba = *reinterpret_cast<const float2*>(Wattn + (size_t)c*32 + tj*2);
            #pragma unroll
            for (int i = 0; i < 4; i++){
                ao[i][0] += av[i]*bo.x; ao[i][1] += av[i]*bo.y;
                ao[i][2] += av[i]*bo.z; ao[i][3] += av[i]*bo.w;
                aa[i][0] += av[i]*ba.x; aa[i][1] += av[i]*ba.y;
            }
        }
        __syncthreads();                 // qT consumed
        float* oaS = (float*)smem;       // [64][96]
        #pragma unroll
        for (int i = 0; i < 4; i++){
            int r = ti*4 + i;
            #pragma unroll
            for (int j = 0; j < 4; j++) oaS[r*96 + tj*4 + j] = ao[i][j] + boff[tj*4 + j];
            oaS[r*96 + 64 + tj*2 + 0] = aa[i][0] + battn[tj*2 + 0];
            oaS[r*96 + 64 + tj*2 + 1] = aa[i][1] + battn[tj*2 + 1];
        }
        __syncthreads();

        // epilogue: per (r,h) softmax + coords/wsb  (coords padded to float4/pt)
        for (int idx = tid; idx < 512; idx += 256){
            int r = idx >> 3, h = idx & 7;
            int m = m0 + r;
            const float* row = oaS + r*96;
            float a0 = row[64 + h*4 + 0], a1 = row[64 + h*4 + 1];
            float a2 = row[64 + h*4 + 2], a3 = row[64 + h*4 + 3];
            float mx = fmaxf(fmaxf(a0, a1), fmaxf(a2, a3));
            float e0 = __expf(a0 - mx), e1 = __expf(a1 - mx);
            float e2 = __expf(a2 - mx), e3 = __expf(a3 - mx);
            float inv = 1.f / (e0 + e1 + e2 + e3);
            float wp[4] = {e0*inv, e1*inv, e2*inv, e3*inv};
            float cxp = cen_s[r][0], cyp = cen_s[r][1];
            float* cp = coords + ((size_t)m*8 + h)*16;
            float wsum = 0.f;
            #pragma unroll
            for (int p = 0; p < 4; p++){
                float x = cxp + row[h*8 + p*2 + 0];
                float y = cyp + row[h*8 + p*2 + 1];
                cp[p*4 + 0] = x; cp[p*4 + 1] = y; cp[p*4 + 2] = wp[p];
                float fx = floorf(x), fy = floorf(y);
                int x0 = (int)fx, y0 = (int)fy;
                float wx = x - fx, wy = y - fy;
                bool vx0 = (unsigned)x0 < WWF, vx1 = (unsigned)(x0+1) < WWF;
                bool vy0 = (unsigned)y0 < HHF, vy1 = (unsigned)(y0+1) < HHF;
                float w = wp[p];
                if (vy0 && vx0) wsum += w*(1.f-wx)*(1.f-wy);
                if (vy0 && vx1) wsum += w*wx*(1.f-wy);
                if (vy1 && vx0) wsum += w*(1.f-wx)*wy;
                if (vy1 && vx1) wsum += w*wx*wy;
            }
            wsb[(size_t)m*8 + h] = wsum;
        }
    } else if (bx < 113){
        // ---------------- prep role ----------------
        const int bxp = bx - 64;
        if (bxp < 32){
            // WgT head tile: h = bxp>>2, n0 = (bxp&3)*64 ; Wout staged in 128-row halves
            float (*WoutS)[64] = (float(*)[64])smem;                 // [128][64]
            float (*DhT)[36]   = (float(*)[36])(smem + 128*64*4);    // [64][36]
            const int h   = bxp >> 2;
            const int n0  = (bxp & 3) * 64;
            const int j   = tid >> 3;
            const int nn0 = (tid & 7) * 8;
            float acc[8];
            #pragma unroll
            for (int u = 0; u < 8; u++) acc[u] = 0.f;
            for (int p = 0; p < 2; p++){
                if (p) __syncthreads();
                #pragma unroll
                for (int i = 0; i < 8; i++){
                    int idx = tid + i*256;
                    int t = idx >> 4, c4 = (idx & 15)*4;
                    *reinterpret_cast<float4*>(&WoutS[t][c4]) =
                        *reinterpret_cast<const float4*>(Wout + (size_t)(p*128 + t)*256 + n0 + c4);
                }
                __syncthreads();
                const float* wdop = Wdo + (size_t)(h*32 + j)*256 + p*128;
                for (int t = 0; t < 128; t++){
                    float wdo = wdop[t];
                    float4 w0 = *reinterpret_cast<const float4*>(&WoutS[t][nn0]);
                    float4 w1 = *reinterpret_cast<const float4*>(&WoutS[t][nn0+4]);
                    acc[0] += wdo*w0.x; acc[1] += wdo*w0.y; acc[2] += wdo*w0.z; acc[3] += wdo*w0.w;
                    acc[4] += wdo*w1.x; acc[5] += wdo*w1.y; acc[6] += wdo*w1.z; acc[7] += wdo*w1.w;
                }
            }
            #pragma unroll
            for (int u = 0; u < 8; u++) DhT[nn0 + u][j] = acc[u];
            __syncthreads();
            float wv[32];
            #pragma unroll
            for (int q4 = 0; q4 < 8; q4++){
                float4 v = *reinterpret_cast<const float4*>(Wval + (size_t)tid*256 + h*32 + q4*4);
                wv[q4*4+0]=v.x; wv[q4*4+1]=v.y; wv[q4*4+2]=v.z; wv[q4*4+3]=v.w;
            }
            for (int nn = 0; nn < 64; nn++){
                float s = 0.f;
                #pragma unroll
                for (int q4 = 0; q4 < 8; q4++){
                    float4 d = *reinterpret_cast<const float4*>(&DhT[nn][q4*4]);
                    s += wv[q4*4+0]*d.x + wv[q4*4+1]*d.y + wv[q4*4+2]*d.z + wv[q4*4+3]*d.w;
                }
                WgT[(size_t)(n0 + nn)*KTOT + h*256 + tid] = f2bf(s);
            }
        } else if (bxp < 48){
            // WgT qe tile: (Wq@Wout)^T
            const int idx2 = bxp - 32;
            const int n0 = (idx2 >> 2) * 64;
            const int c0 = (idx2 & 3) * 64;
            float (*WoutS)[64] = (float(*)[64])smem;                 // [64][64]
            float (*WqS)[65]   = (float(*)[65])(smem + 64*64*4);     // [64][65]
            const int lc  = tid & 63;
            const int grp = tid >> 6;
            float acc[16];
            #pragma unroll
            for (int u = 0; u < 16; u++) acc[u] = 0.f;
            for (int p = 0; p < 4; p++){
                if (p) __syncthreads();
                #pragma unroll
                for (int i = 0; i < 4; i++){
                    int idx = tid + i*256;
                    int r = idx >> 4, c4 = (idx & 15)*4;
                    *reinterpret_cast<float4*>(&WoutS[r][c4]) =
                        *reinterpret_cast<const float4*>(Wout + (size_t)(p*64 + r)*256 + n0 + c4);
                    float4 wq = *reinterpret_cast<const float4*>(Wq + (size_t)(c0 + r)*256 + p*64 + c4);
                    WqS[r][c4+0]=wq.x; WqS[r][c4+1]=wq.y; WqS[r][c4+2]=wq.z; WqS[r][c4+3]=wq.w;
                }
                __syncthreads();
                for (int jj = 0; jj < 64; jj++){
                    float wq = WqS[lc][jj];
                    #pragma unroll
                    for (int u4 = 0; u4 < 4; u4++){
                        float4 w = *reinterpret_cast<const float4*>(&WoutS[jj][grp*16 + u4*4]);
                        acc[u4*4+0] += wq*w.x; acc[u4*4+1] += wq*w.y;
                        acc[u4*4+2] += wq*w.z; acc[u4*4+3] += wq*w.w;
                    }
                }
            }
            #pragma unroll
            for (int u = 0; u < 16; u++)
                WgT[(size_t)(n0 + grp*16 + u)*KTOT + 2048 + c0 + lc] = f2bf(acc[u]);
        } else {
            // Bh[8][256] and bconst[256]
            float (*vhS)[256] = (float(*)[256])smem;
            const int t = tid;
            for (int h = 0; h < 8; h++){
                float s = 0.f;
                #pragma unroll
                for (int jj = 0; jj < 32; jj++)
                    s += bval[h*32 + jj] * Wdo[(size_t)(h*32 + jj)*256 + t];
                vhS[h][t] = s;
            }
            __syncthreads();
            float bh[8];
            #pragma unroll
            for (int h = 0; h < 8; h++) bh[h] = 0.f;
            float bc = 0.f;
            for (int k = 0; k < 256; k++){
                float w  = Wout[(size_t)k*256 + t];
                bc += (bdo[k] + bq[k]) * w;
                #pragma unroll
                for (int h = 0; h < 8; h++) bh[h] += vhS[h][k] * w;
            }
            #pragma unroll
            for (int h = 0; h < 8; h++) Bh[h*256 + t] = bh[h];
            bconst[t] = bc + bout[t];
        }
    } else {
        // ---------------- transpose role: 64x64 tile via f32 LDS ----------------
        const int bxt = bx - 113;
        const int b   = bxt / 2500;
        const int r2  = bxt - b*2500;
        const int c0  = (r2 / 625) * 64;
        const int p0  = (r2 - (r2/625)*625) * 64;
        float (*T)[67] = (float(*)[67])smem;       // [64 p][67]
        const float* src = bev + (size_t)b * DD * HWF;
        const int tx = tid & 15, ty = tid >> 4;
        #pragma unroll
        for (int q = 0; q < 4; q++){
            int c = c0 + q*16 + ty;
            float4 v = *reinterpret_cast<const float4*>(src + (size_t)c*HWF + p0 + tx*4);
            T[tx*4+0][q*16+ty] = v.x; T[tx*4+1][q*16+ty] = v.y;
            T[tx*4+2][q*16+ty] = v.z; T[tx*4+3][q*16+ty] = v.w;
        }
        __syncthreads();
        const int sx = tid & 7, sy = tid >> 3;     // sy 0..31
        unsigned short* dst = bevT + (size_t)b * HWF * DD;
        #pragma unroll
        for (int s = 0; s < 2; s++){
            int p = s*32 + sy;
            float v[8];
            #pragma unroll
            for (int u = 0; u < 8; u++) v[u] = T[p][sx*8+u];
            store_bf16x8(dst + (size_t)(p0 + p)*DD + c0 + sx*8, v);
        }
    }
}

// ================== K2: gatherfinal — gather straight into LDS A-panel + MFMA ======
// grid 256: 16-row m-tiles x full N=256.
// Phase 1: the gather inner loop (bit-identical to the old gather kernel, including
//          the bf16 rounding of acc) writes As[row][h*256+c] with the XOR-16B swizzle.
// Phase 2: out = [As | bf16(qe)] @ WgT^T + wsb@Bh + bconst  (MFMA 16x16x32 bf16).
// D layout: col=lane&15, row=(lane>>4)*4+reg (m89-verified).
template<bool TRANS>
__global__ __launch_bounds__(256) void gatherfinal_kernel(
    const unsigned short* __restrict__ bevT,   // (B,HW,C) bf16 bits
    const float* __restrict__ bev,             // (B,C,HW) f32 (fallback)
    const float* __restrict__ coords,          // per (m,h): 4 x float4 {x,y,w,pad}
    const float* __restrict__ qe,              // [4096][256] f32
    const unsigned short* __restrict__ WgT,    // [256][KTOT] bf16
    const float* __restrict__ wsb,             // [4096][8]
    const float* __restrict__ Bh,              // [8][256]
    const float* __restrict__ bconst,          // [256]
    float* __restrict__ out)                   // [4096][256]
{
    __shared__ __align__(16) unsigned short As[16*2048];   // 64 KB, swizzled
    const int m0  = blockIdx.x * 16;
    const int b   = m0 >> 10;
    const int tid = threadIdx.x;

    {   // ---- phase 1: gather into As ----
        const int sub = tid & 31;
        const int grp = tid >> 5;
        for (int it = 0; it < 16; it++){
            int rh  = it*8 + grp;          // 0..127
            int row = rh >> 3;
            int h   = rh & 7;
            int m   = m0 + row;
            float acc[8] = {0.f,0.f,0.f,0.f,0.f,0.f,0.f,0.f};
            const float* cp = coords + ((size_t)m*8 + h)*16;

            #pragma unroll
            for (int p = 0; p < 4; p++){
                float4 c4 = *reinterpret_cast<const float4*>(cp + p*4);
                float x = c4.x, y = c4.y, w = c4.z;
                float fx = floorf(x), fy = floorf(y);
                int x0 = (int)fx, y0 = (int)fy;
                float wx = x - fx, wy = y - fy;
                int   xs[4]  = {x0, x0+1, x0,   x0+1};
                int   ys[4]  = {y0, y0,   y0+1, y0+1};
                float ws4[4] = {w*(1.f-wx)*(1.f-wy), w*wx*(1.f-wy), w*(1.f-wx)*wy, w*wx*wy};
                #pragma unroll
                for (int cidx = 0; cidx < 4; cidx++){
                    int xi = xs[cidx], yi = ys[cidx];
                    if ((unsigned)xi < WWF && (unsigned)yi < HHF){
                        float wgt = ws4[cidx];
                        if (TRANS){
                            const unsigned short* rowp =
                                bevT + (((size_t)b*HWF + yi*WWF + xi)*DD + sub*8);
                            float v[8]; load_bf16x8(rowp, v);
                            #pragma unroll
                            for (int i = 0; i < 8; i++) acc[i] += wgt * v[i];
                        } else {
                            size_t base = ((size_t)b*DD + sub*8)*HWF + (size_t)(yi*WWF + xi);
                            #pragma unroll
                            for (int i = 0; i < 8; i++) acc[i] += wgt * bev[base + (size_t)i*HWF];
                        }
                    }
                }
            }
            // pack to bf16 (same rounding as old g store) and write swizzled LDS
            int4 t;
            t.x = (int)((unsigned)f2bf(acc[0]) | ((unsigned)f2bf(acc[1]) << 16));
            t.y = (int)((unsigned)f2bf(acc[2]) | ((unsigned)f2bf(acc[3]) << 16));
            t.z = (int)((unsigned)f2bf(acc[4]) | ((unsigned)f2bf(acc[5]) << 16));
            t.w = (int)((unsigned)f2bf(acc[6]) | ((unsigned)f2bf(acc[7]) << 16));
            int kbyte = h*512 + sub*16;
            char* dstb = (char*)(As + row*2048);
            *reinterpret_cast<int4*>(dstb + (kbyte ^ ((row & 7) << 4))) = t;
        }
    }
    __syncthreads();

    // ---- phase 2: MFMA ----
    const int w    = tid >> 6;
    const int l    = tid & 63;
    const int lrow = l & 15;
    const int lk   = l >> 4;

    f32x4 acc0 = {0.f,0.f,0.f,0.f};
    f32x4 acc1 = {0.f,0.f,0.f,0.f};
    f32x4 acc2 = {0.f,0.f,0.f,0.f};
    f32x4 acc3 = {0.f,0.f,0.f,0.f};

    const unsigned short* Bp = WgT + (size_t)(w*64 + lrow)*KTOT + lk*8;
    const char* Ab = (const char*)(As + lrow*2048);
    const int asw = (lrow & 7) << 4;

    #pragma unroll 4
    for (int k0 = 0; k0 < 2048; k0 += 32){
        bf16x8 a  = *reinterpret_cast<const bf16x8*>(Ab + (((k0 + lk*8)*2) ^ asw));
        bf16x8 b0 = *reinterpret_cast<const bf16x8*>(Bp + k0);
        bf16x8 b1 = *reinterpret_cast<const bf16x8*>(Bp + 16*KTOT + k0);
        bf16x8 b2 = *reinterpret_cast<const bf16x8*>(Bp + 32*KTOT + k0);
        bf16x8 b3 = *reinterpret_cast<const bf16x8*>(Bp + 48*KTOT + k0);
        acc0 = __builtin_amdgcn_mfma_f32_16x16x32_bf16(a, b0, acc0, 0, 0, 0);
        acc1 = __builtin_amdgcn_mfma_f32_16x16x32_bf16(a, b1, acc1, 0, 0, 0);
        acc2 = __builtin_amdgcn_mfma_f32_16x16x32_bf16(a, b2, acc2, 0, 0, 0);
        acc3 = __builtin_amdgcn_mfma_f32_16x16x32_bf16(a, b3, acc3, 0, 0, 0);
    }
    // residual: k' = 2048..2303 from qe (f32 -> bf16 on the fly)
    const float* Qp = qe + (size_t)(m0 + lrow)*256 + lk*8;
    #pragma unroll
    for (int k0 = 0; k0 < 256; k0 += 32){
        float4 qa = *reinterpret_cast<const float4*>(Qp + k0);
        float4 qb = *reinterpret_cast<const float4*>(Qp + k0 + 4);
        union { unsigned short u[8]; bf16x8 v; } cu;
        cu.u[0]=f2bf(qa.x); cu.u[1]=f2bf(qa.y); cu.u[2]=f2bf(qa.z); cu.u[3]=f2bf(qa.w);
        cu.u[4]=f2bf(qb.x); cu.u[5]=f2bf(qb.y); cu.u[6]=f2bf(qb.z); cu.u[7]=f2bf(qb.w);
        bf16x8 b0 = *reinterpret_cast<const bf16x8*>(Bp + 2048 + k0);
        bf16x8 b1 = *reinterpret_cast<const bf16x8*>(Bp + 16*KTOT + 2048 + k0);
        bf16x8 b2 = *reinterpret_cast<const bf16x8*>(Bp + 32*KTOT + 2048 + k0);
        bf16x8 b3 = *reinterpret_cast<const bf16x8*>(Bp + 48*KTOT + 2048 + k0);
        acc0 = __builtin_amdgcn_mfma_f32_16x16x32_bf16(cu.v, b0, acc0, 0, 0, 0);
        acc1 = __builtin_amdgcn_mfma_f32_16x16x32_bf16(cu.v, b1, acc1, 0, 0, 0);
        acc2 = __builtin_amdgcn_mfma_f32_16x16x32_bf16(cu.v, b2, acc2, 0, 0, 0);
        acc3 = __builtin_amdgcn_mfma_f32_16x16x32_bf16(cu.v, b3, acc3, 0, 0, 0);
    }

    // epilogue: + bconst + wsb@Bh
    float wsrow[4][8];
    #pragma unroll
    for (int i = 0; i < 4; i++){
        int r = m0 + lk*4 + i;
        float4 wa = *reinterpret_cast<const float4*>(wsb + (size_t)r*8);
        float4 wb = *reinterpret_cast<const float4*>(wsb + (size_t)r*8 + 4);
        wsrow[i][0]=wa.x; wsrow[i][1]=wa.y; wsrow[i][2]=wa.z; wsrow[i][3]=wa.w;
        wsrow[i][4]=wb.x; wsrow[i][5]=wb.y; wsrow[i][6]=wb.z; wsrow[i][7]=wb.w;
    }
    const f32x4 accs[4] = {acc0, acc1, acc2, acc3};
    #pragma unroll
    for (int nt = 0; nt < 4; nt++){
        int c = w*64 + nt*16 + lrow;
        float bcv = bconst[c];
        float bhv[8];
        #pragma unroll
        for (int h = 0; h < 8; h++) bhv[h] = Bh[h*256 + c];
        #pragma unroll
        for (int i = 0; i < 4; i++){
            int r = m0 + lk*4 + i;
            float v = accs[nt][i] + bcv;
            #pragma unroll
            for (int h = 0; h < 8; h++) v += wsrow[i][h]*bhv[h];
            out[(size_t)r*256 + c] = v;
        }
    }
}

extern "C" void kernel_launch(void* const* d_in, const int* in_sizes, int n_in,
                              void* d_out, int out_size, void* d_ws, size_t ws_size,
                              hipStream_t stream)
{
    (void)in_sizes; (void)n_in; (void)out_size;
    float* out = (float*)d_out;
    char*  ws  = (char*)d_ws;

    // workspace layout (256B-aligned); bevT last so the fallback tier works
    const size_t OF_CO  = 0;                                  // coords 4096*8*64B
    const size_t OF_WSB = OF_CO  + (size_t)4096*8*64;         //  2,097,152
    const size_t OF_WGT = OF_WSB + (size_t)4096*8*4;          //  2,228,224
    const size_t OF_BH  = OF_WGT + (size_t)256*KTOT*2;        //  3,407,872
    const size_t OF_BC  = OF_BH  + (size_t)8*256*4;           //  3,416,064
    const size_t OF_BT  = OF_BC  + 1024;                      //  3,417,088
    const size_t NEED   = OF_BT  + (size_t)BB*HWF*DD*2;       // 85,337,088

    float*          coords = (float*)(ws + OF_CO);
    float*          wsb    = (float*)(ws + OF_WSB);
    unsigned short* WgT    = (unsigned short*)(ws + OF_WGT);
    float*          Bh     = (float*)(ws + OF_BH);
    float*          bconst = (float*)(ws + OF_BC);
    unsigned short* bevT   = (unsigned short*)(ws + OF_BT);

    const float* qe    = (const float*)d_in[0];
    const float* ctrl  = (const float*)d_in[1];
    const float* bev   = (const float*)d_in[2];
    const float* pc    = (const float*)d_in[4];
    const float* Wq    = (const float*)d_in[5];
    const float* bq    = (const float*)d_in[6];
    const float* Wval  = (const float*)d_in[7];
    const float* bval  = (const float*)d_in[8];
    const float* Woff  = (const float*)d_in[9];
    const float* boff  = (const float*)d_in[10];
    const float* Wattn = (const float*)d_in[11];
    const float* battn = (const float*)d_in[12];
    const float* Wdo   = (const float*)d_in[13];
    const float* bdo   = (const float*)d_in[14];
    const float* Wout  = (const float*)d_in[15];
    const float* bout  = (const float*)d_in[16];

    const bool haveT = (ws_size >= NEED);

    // K1: oa (64) + prep (49) + transpose (10000) in one grid
    front_kernel<<<haveT ? 10113 : 113, 256, 0, stream>>>(
        qe, ctrl, pc, Wq, bq, Wval, bval, Woff, boff, Wattn, battn,
        Wdo, bdo, Wout, bout, bev, bevT, WgT, Bh, bconst, coords, wsb);
    // K2: gather fused with back-end GEMM (MFMA bf16)
    if (haveT)
        gatherfinal_kernel<true ><<<256, 256, 0, stream>>>(
            bevT, bev, coords, qe, WgT, wsb, Bh, bconst, out);
    else
        gatherfinal_kernel<false><<<256, 256, 0, stream>>>(
            bevT, bev, coords, qe, WgT, wsb, Bh, bconst, out);
}

// Round 5
// 418.032 us; speedup vs baseline: 1.1251x; 1.1251x over previous
//
#include <hip/hip_runtime.h>

#define BB 4
#define NN 1024
#define DD 256
#define NHEADS 8
#define NPTS 4
#define NKSAMP 10
#define HHF 200
#define WWF 200
#define HWF (HHF*WWF)

typedef __attribute__((ext_vector_type(8))) short bf16x8;
typedef __attribute__((ext_vector_type(4))) float f32x4;

__device__ __forceinline__ unsigned short f2bf(float f){
    unsigned u = __float_as_uint(f);
    return (unsigned short)((u + 0x7FFFu + ((u >> 16) & 1u)) >> 16);
}
__device__ __forceinline__ void load_bf16x8(const unsigned short* p, float* v){
    int4 t = *reinterpret_cast<const int4*>(p);
    unsigned q0 = (unsigned)t.x, q1 = (unsigned)t.y, q2 = (unsigned)t.z, q3 = (unsigned)t.w;
    v[0] = __uint_as_float(q0 << 16); v[1] = __uint_as_float(q0 & 0xFFFF0000u);
    v[2] = __uint_as_float(q1 << 16); v[3] = __uint_as_float(q1 & 0xFFFF0000u);
    v[4] = __uint_as_float(q2 << 16); v[5] = __uint_as_float(q2 & 0xFFFF0000u);
    v[6] = __uint_as_float(q3 << 16); v[7] = __uint_as_float(q3 & 0xFFFF0000u);
}
__device__ __forceinline__ void store_bf16x8(unsigned short* p, const float* v){
    int4 t;
    t.x = (int)((unsigned)f2bf(v[0]) | ((unsigned)f2bf(v[1]) << 16));
    t.y = (int)((unsigned)f2bf(v[2]) | ((unsigned)f2bf(v[3]) << 16));
    t.z = (int)((unsigned)f2bf(v[4]) | ((unsigned)f2bf(v[5]) << 16));
    t.w = (int)((unsigned)f2bf(v[6]) | ((unsigned)f2bf(v[7]) << 16));
    *reinterpret_cast<int4*>(p) = t;
}

// ================== K0: prep — all weight-only algebra ==================
// blocks 0..15 : WgT2[n][k]      = (Wdo@Wout)^T          (k<256)
// blocks 16..31: WgT2[n][256+k]  = (Wq @Wout)^T
// blocks 32..35: Wqoa[c][96]     = Wq@[Woff|Wattn]  (+ bqoa on block 32)
// block  36    : bconst[n] = (bdo+bq)@Wout + bout
// blocks 37..40: WvalT[n][c] = Wval^T (bf16)
__global__ __launch_bounds__(256) void prep_kernel(
    const float* __restrict__ Wq,   const float* __restrict__ bq,
    const float* __restrict__ Wval,
    const float* __restrict__ Woff, const float* __restrict__ boff,
    const float* __restrict__ Wattn,const float* __restrict__ battn,
    const float* __restrict__ Wdo,  const float* __restrict__ bdo,
    const float* __restrict__ Wout, const float* __restrict__ bout,
    unsigned short* __restrict__ WgT2,
    float* __restrict__ Wqoa, float* __restrict__ bqoa,
    float* __restrict__ bconst,
    unsigned short* __restrict__ WvalT)
{
    __shared__ __align__(16) char smem[42496];
    const int bx = blockIdx.x, tid = threadIdx.x;

    if (bx < 32){
        // (W@Wout)^T tile, W = Wdo (bx<16) or Wq (bx>=16)
        const float* W  = (bx < 16) ? Wdo : Wq;
        const int dstoff = (bx < 16) ? 0 : 256;
        const int idx2 = bx & 15;
        const int n0 = (idx2 >> 2) * 64;
        const int k0 = (idx2 & 3) * 64;
        float (*WoutS)[64] = (float(*)[64])smem;                 // [64][64]
        float (*WS)[65]    = (float(*)[65])(smem + 64*64*4);     // [64][65]
        const int lc  = tid & 63;
        const int grp = tid >> 6;
        float acc[16];
        #pragma unroll
        for (int u = 0; u < 16; u++) acc[u] = 0.f;
        for (int p = 0; p < 4; p++){
            if (p) __syncthreads();
            #pragma unroll
            for (int i = 0; i < 4; i++){
                int idx = tid + i*256;
                int r = idx >> 4, c4 = (idx & 15)*4;
                *reinterpret_cast<float4*>(&WoutS[r][c4]) =
                    *reinterpret_cast<const float4*>(Wout + (size_t)(p*64 + r)*256 + n0 + c4);
                float4 wv = *reinterpret_cast<const float4*>(W + (size_t)(k0 + r)*256 + p*64 + c4);
                WS[r][c4+0]=wv.x; WS[r][c4+1]=wv.y; WS[r][c4+2]=wv.z; WS[r][c4+3]=wv.w;
            }
            __syncthreads();
            for (int jj = 0; jj < 64; jj++){
                float wq = WS[lc][jj];
                #pragma unroll
                for (int u4 = 0; u4 < 4; u4++){
                    float4 w = *reinterpret_cast<const float4*>(&WoutS[jj][grp*16 + u4*4]);
                    acc[u4*4+0] += wq*w.x; acc[u4*4+1] += wq*w.y;
                    acc[u4*4+2] += wq*w.z; acc[u4*4+3] += wq*w.w;
                }
            }
        }
        #pragma unroll
        for (int u = 0; u < 16; u++)
            WgT2[(size_t)(n0 + grp*16 + u)*512 + dstoff + k0 + lc] = f2bf(acc[u]);
    } else if (bx < 36){
        // Wqoa rows c0..c0+63 (round-0 proven code); bx==32 also does bqoa
        const int c0 = (bx - 32) * 64;
        float (*WS)[96]  = (float(*)[96])smem;                   // [64][96]
        float (*WqS)[65] = (float(*)[65])(smem + 64*96*4);       // [64][65]
        const int lc  = tid & 63;
        const int grp = tid >> 6;
        float acc[24];
        #pragma unroll
        for (int u = 0; u < 24; u++) acc[u] = 0.f;
        float bacc = 0.f;
        for (int p = 0; p < 4; p++){
            if (p) __syncthreads();
            #pragma unroll
            for (int i = 0; i < 6; i++){
                int idx = tid + i*256;
                int r = idx / 24, c4 = (idx % 24) * 4;
                float4 v;
                if (c4 < 64) v = *reinterpret_cast<const float4*>(Woff  + (size_t)(p*64 + r)*64 + c4);
                else         v = *reinterpret_cast<const float4*>(Wattn + (size_t)(p*64 + r)*32 + (c4 - 64));
                WS[r][c4+0]=v.x; WS[r][c4+1]=v.y; WS[r][c4+2]=v.z; WS[r][c4+3]=v.w;
            }
            #pragma unroll
            for (int i = 0; i < 4; i++){
                int idx = tid + i*256;
                int r = idx >> 4, c4 = (idx & 15)*4;
                float4 wq = *reinterpret_cast<const float4*>(Wq + (size_t)(c0 + r)*256 + p*64 + c4);
                WqS[r][c4+0]=wq.x; WqS[r][c4+1]=wq.y; WqS[r][c4+2]=wq.z; WqS[r][c4+3]=wq.w;
            }
            __syncthreads();
            for (int jj = 0; jj < 64; jj++){
                float wq = WqS[lc][jj];
                #pragma unroll
                for (int u4 = 0; u4 < 6; u4++){
                    float4 w = *reinterpret_cast<const float4*>(&WS[jj][grp*24 + u4*4]);
                    acc[u4*4+0] += wq*w.x; acc[u4*4+1] += wq*w.y;
                    acc[u4*4+2] += wq*w.z; acc[u4*4+3] += wq*w.w;
                }
            }
            if (bx == 32 && tid < 96){
                for (int jj = 0; jj < 64; jj++) bacc += bq[p*64 + jj] * WS[jj][tid];
            }
        }
        #pragma unroll
        for (int u = 0; u < 24; u++)
            Wqoa[(size_t)(c0 + lc)*96 + grp*24 + u] = acc[u];
        if (bx == 32 && tid < 96)
            bqoa[tid] = bacc + (tid < 64 ? boff[tid] : battn[tid - 64]);
    } else if (bx == 36){
        float s = 0.f;
        for (int k = 0; k < 256; k++) s += (bdo[k] + bq[k]) * Wout[(size_t)k*256 + tid];
        bconst[tid] = s + bout[tid];
    } else {
        // WvalT slab: n0 = (bx-37)*64 ; LDS-transpose 64x64 tiles
        const int n0 = (bx - 37) * 64;
        float (*T)[67] = (float(*)[67])smem;                     // [64 n][67]
        const int tx = tid & 15, ty = tid >> 4;
        for (int ct = 0; ct < 4; ct++){
            if (ct) __syncthreads();
            #pragma unroll
            for (int q = 0; q < 4; q++){
                int c = ct*64 + q*16 + ty;
                float4 v = *reinterpret_cast<const float4*>(Wval + (size_t)c*256 + n0 + tx*4);
                T[tx*4+0][q*16+ty] = v.x; T[tx*4+1][q*16+ty] = v.y;
                T[tx*4+2][q*16+ty] = v.z; T[tx*4+3][q*16+ty] = v.w;
            }
            __syncthreads();
            const int sx = tid & 7, sy = tid >> 3;
            #pragma unroll
            for (int s = 0; s < 2; s++){
                int n = s*32 + sy;
                float v[8];
                #pragma unroll
                for (int u = 0; u < 8; u++) v[u] = T[n][sx*8+u];
                store_bf16x8(WvalT + (size_t)(n0 + n)*256 + ct*64 + sx*8, v);
            }
        }
    }
}

// ================== K1: value (MFMA bev@Wval+bval -> bf16, pixel-major) | oa ========
// blocks [0,1252): value — 128-pixel tile, LDS-transpose per 64-ch chunk, MFMA vs
//                  WvalT, D->LDS->contiguous 64KB store. Reads 512B-granular.
// blocks [1252,1316): oa — coords/softmax straight from qe via Wqoa (round-0 math).
__global__ __launch_bounds__(256) void valoa_kernel(
    const float* __restrict__ bev,
    const unsigned short* __restrict__ WvalT,
    const float* __restrict__ bval,
    const float* __restrict__ qe, const float* __restrict__ ctrl,
    const float* __restrict__ pc,
    const float* __restrict__ Wqoa, const float* __restrict__ bqoa,
    unsigned short* __restrict__ value,
    float* __restrict__ coords)
{
    __shared__ __align__(16) char smem[69632];
    __shared__ float cen_s[64][2];
    const int bx = blockIdx.x, tid = threadIdx.x;

    if (bx < 1252){
        // ---------------- value role ----------------
        const int tile = bx % 313;
        const int b    = bx / 313;
        const int p0   = tile * 128;
        const int vld  = (HWF - p0 < 128) ? (HWF - p0) : 128;
        const int w = tid >> 6, l = tid & 63, lrow = l & 15, lk = l >> 4;

        f32x4 acc[8][4];
        #pragma unroll
        for (int mt = 0; mt < 8; mt++)
            #pragma unroll
            for (int nt = 0; nt < 4; nt++) acc[mt][nt] = (f32x4){0.f,0.f,0.f,0.f};

        const int po   = (tid & 31) * 4;
        const int crow = tid >> 5;                         // 0..7
        const int poc  = (p0 + po + 3 < HWF) ? po : (HWF - 4 - p0);  // clamp (tail)

        // LDS T: bf16 [128 pix][128 c-slots, 256B rows], c-index XOR-swizzled.
        for (int kc = 0; kc < 4; kc++){
            if (kc) __syncthreads();
            #pragma unroll
            for (int i = 0; i < 8; i++){
                int c = kc*64 + crow + i*8;
                float4 v = *reinterpret_cast<const float4*>(
                    bev + ((size_t)b*DD + c)*HWF + p0 + poc);
                int cs_base = crow + i*8;
                #pragma unroll
                for (int u = 0; u < 4; u++){
                    int p  = po + u;
                    int cs = cs_base ^ ((p & 7) << 3);
                    *(unsigned short*)(smem + p*256 + cs*2) = f2bf(((const float*)&v)[u]);
                }
            }
            __syncthreads();
            #pragma unroll
            for (int ks = 0; ks < 2; ks++){
                bf16x8 bfr[4];
                #pragma unroll
                for (int nt = 0; nt < 4; nt++)
                    bfr[nt] = *reinterpret_cast<const bf16x8*>(
                        WvalT + (size_t)(w*64 + nt*16 + lrow)*256 + kc*64 + ks*32 + lk*8);
                #pragma unroll
                for (int mt = 0; mt < 8; mt++){
                    int pix = mt*16 + lrow;
                    int kb  = (ks*32 + lk*8) ^ ((pix & 7) << 3);
                    bf16x8 a = *reinterpret_cast<const bf16x8*>(smem + pix*256 + kb*2);
                    acc[mt][0] = __builtin_amdgcn_mfma_f32_16x16x32_bf16(a, bfr[0], acc[mt][0], 0,0,0);
                    acc[mt][1] = __builtin_amdgcn_mfma_f32_16x16x32_bf16(a, bfr[1], acc[mt][1], 0,0,0);
                    acc[mt][2] = __builtin_amdgcn_mfma_f32_16x16x32_bf16(a, bfr[2], acc[mt][2], 0,0,0);
                    acc[mt][3] = __builtin_amdgcn_mfma_f32_16x16x32_bf16(a, bfr[3], acc[mt][3], 0,0,0);
                }
            }
        }
        __syncthreads();
        // D (+bval) -> LDS bf16 [128 pix][512B rows], byte-XOR swizzle
        #pragma unroll
        for (int nt = 0; nt < 4; nt++){
            int n = w*64 + nt*16 + lrow;
            float bv = bval[n];
            #pragma unroll
            for (int mt = 0; mt < 8; mt++)
                #pragma unroll
                for (int i = 0; i < 4; i++){
                    int pix  = mt*16 + lk*4 + i;
                    int byte = (pix*512 + n*2) ^ ((pix & 7) << 4);
                    *(unsigned short*)(smem + byte) = f2bf(acc[mt][nt][i] + bv);
                }
        }
        __syncthreads();
        unsigned short* vrow = value + ((size_t)b*HWF + p0)*256;
        #pragma unroll
        for (int j = 0; j < 16; j++){
            int chunk = j*256 + tid;
            int pix = chunk >> 5, inner = chunk & 31;
            if (pix < vld){
                int byte = (pix*512 + inner*16) ^ ((pix & 7) << 4);
                int4 v = *reinterpret_cast<const int4*>(smem + byte);
                *reinterpret_cast<int4*>(vrow + (size_t)pix*256 + inner*8) = v;
            }
        }
    } else {
        // ---------------- oa role ----------------
        const int m0 = (bx - 1252) * 64;
        float (*As)[68] = (float(*)[68])smem;      // qe^T [256][68] = 69,632 B
        {
            int r  = tid >> 2;
            int kb = (tid & 3) * 4;
            #pragma unroll
            for (int kk = 0; kk < 16; kk++){
                int k = kb + kk*16;
                float4 v = *reinterpret_cast<const float4*>(qe + (size_t)(m0 + r)*256 + k);
                As[k+0][r] = v.x; As[k+1][r] = v.y; As[k+2][r] = v.z; As[k+3][r] = v.w;
            }
        }
        if (tid < 64){
            int m = m0 + tid;
            float cx[4], cy[4];
            #pragma unroll
            for (int i = 0; i < 4; i++){
                cx[i] = ctrl[(size_t)m*8 + i*2 + 0];
                cy[i] = ctrl[(size_t)m*8 + i*2 + 1];
            }
            float lox = pc[0], loy = pc[1];
            float spx = pc[3] - lox, spy = pc[4] - loy;
            float sx = 0.f, sy = 0.f;
            for (int k = 0; k < NKSAMP; k++){
                float t = (float)k / (float)(NKSAMP - 1);
                float u = 1.f - t;
                float c0 = u*u*u, c1 = 3.f*u*u*t, c2 = 3.f*u*t*t, c3 = t*t*t;
                float dx = c0*cx[0] + c1*cx[1] + c2*cx[2] + c3*cx[3];
                float dy = c0*cy[0] + c1*cy[1] + c2*cy[2] + c3*cy[3];
                float rx = fminf(fmaxf((dx - lox)/spx, 0.01f), 0.99f);
                float ry = fminf(fmaxf((dy - loy)/spy, 0.01f), 0.99f);
                sx += rx; sy += ry;
            }
            cen_s[tid][0] = (sx / (float)NKSAMP) * (float)WWF - 0.5f;
            cen_s[tid][1] = (sy / (float)NKSAMP) * (float)HHF - 0.5f;
        }
        __syncthreads();
        const int ti = tid & 15;
        const int tj = tid >> 4;
        float ao[4][4], aa[4][2];
        #pragma unroll
        for (int i = 0; i < 4; i++){
            #pragma unroll
            for (int j = 0; j < 4; j++) ao[i][j] = 0.f;
            aa[i][0] = 0.f; aa[i][1] = 0.f;
        }
        #pragma unroll 4
        for (int c = 0; c < 256; c++){
            float4 a = *reinterpret_cast<const float4*>(&As[c][ti*4]);
            float av[4] = {a.x, a.y, a.z, a.w};
            float4 bo = *reinterpret_cast<const float4*>(Wqoa + (size_t)c*96 + tj*4);
            float2 ba = *reinterpret_cast<const float2*>(Wqoa + (size_t)c*96 + 64 + tj*2);
            #pragma unroll
            for (int i = 0; i < 4; i++){
                ao[i][0] += av[i]*bo.x; ao[i][1] += av[i]*bo.y;
                ao[i][2] += av[i]*bo.z; ao[i][3] += av[i]*bo.w;
                aa[i][0] += av[i]*ba.x; aa[i][1] += av[i]*ba.y;
            }
        }
        __syncthreads();
        float* oaS = (float*)smem;       // [64][96]
        #pragma unroll
        for (int i = 0; i < 4; i++){
            int r = ti*4 + i;
            #pragma unroll
            for (int j = 0; j < 4; j++) oaS[r*96 + tj*4 + j] = ao[i][j] + bqoa[tj*4 + j];
            oaS[r*96 + 64 + tj*2 + 0] = aa[i][0] + bqoa[64 + tj*2 + 0];
            oaS[r*96 + 64 + tj*2 + 1] = aa[i][1] + bqoa[64 + tj*2 + 1];
        }
        __syncthreads();
        for (int idx = tid; idx < 512; idx += 256){
            int r = idx >> 3, h = idx & 7;
            int m = m0 + r;
            const float* row = oaS + r*96;
            float a0 = row[64 + h*4 + 0], a1 = row[64 + h*4 + 1];
            float a2 = row[64 + h*4 + 2], a3 = row[64 + h*4 + 3];
            float mx = fmaxf(fmaxf(a0, a1), fmaxf(a2, a3));
            float e0 = __expf(a0 - mx), e1 = __expf(a1 - mx);
            float e2 = __expf(a2 - mx), e3 = __expf(a3 - mx);
            float inv = 1.f / (e0 + e1 + e2 + e3);
            float wp[4] = {e0*inv, e1*inv, e2*inv, e3*inv};
            float cxp = cen_s[r][0], cyp = cen_s[r][1];
            float* cp = coords + ((size_t)m*8 + h)*16;
            #pragma unroll
            for (int p = 0; p < 4; p++){
                cp[p*4 + 0] = cxp + row[h*8 + p*2 + 0];
                cp[p*4 + 1] = cyp + row[h*8 + p*2 + 1];
                cp[p*4 + 2] = wp[p];
                cp[p*4 + 3] = 0.f;
            }
        }
    }
}

// ================== K2: gather — 1KB per (m,h) from value (L3-resident) ============
__global__ __launch_bounds__(256) void gather2_kernel(
    const unsigned short* __restrict__ value,   // (B,HW,256) bf16
    const float* __restrict__ coords,           // per (m,h): 4 x {x,y,w,pad}
    unsigned short* __restrict__ g2)            // [4096][256] bf16
{
    const int pair0 = blockIdx.x * 64;
    const int tid   = threadIdx.x;
    const int slice = tid & 3;                  // 8 channels each
    const int pair  = pair0 + (tid >> 2);
    const int m = pair >> 3, h = pair & 7, b = m >> 10;
    const float* cp = coords + (size_t)pair * 16;

    float acc[8] = {0.f,0.f,0.f,0.f,0.f,0.f,0.f,0.f};
    #pragma unroll
    for (int p = 0; p < 4; p++){
        float4 c4 = *reinterpret_cast<const float4*>(cp + p*4);
        float x = c4.x, y = c4.y, wq = c4.z;
        float fx = floorf(x), fy = floorf(y);
        int x0 = (int)fx, y0 = (int)fy;
        float wx = x - fx, wy = y - fy;
        int   xs[4]  = {x0, x0+1, x0,   x0+1};
        int   ys[4]  = {y0, y0,   y0+1, y0+1};
        float ws4[4] = {wq*(1.f-wx)*(1.f-wy), wq*wx*(1.f-wy), wq*(1.f-wx)*wy, wq*wx*wy};
        #pragma unroll
        for (int ci = 0; ci < 4; ci++){
            int xi = xs[ci], yi = ys[ci];
            if ((unsigned)xi < WWF && (unsigned)yi < HHF){
                const unsigned short* vp =
                    value + ((size_t)b*HWF + yi*WWF + xi)*256 + h*32 + slice*8;
                float v[8]; load_bf16x8(vp, v);
                float wgt = ws4[ci];
                #pragma unroll
                for (int i = 0; i < 8; i++) acc[i] += wgt * v[i];
            }
        }
    }
    store_bf16x8(g2 + (size_t)m*256 + h*32 + slice*8, acc);
}

// ================== K3: final — out = [g2 | bf16(qe)] @ WgT2^T + bconst =============
// grid 256: 16-row tiles, K=512, 16KB swizzled LDS A (high occupancy).
__global__ __launch_bounds__(256) void final2_kernel(
    const unsigned short* __restrict__ g2,     // [4096][256] bf16
    const float* __restrict__ qe,              // [4096][256] f32
    const unsigned short* __restrict__ WgT2,   // [256 n][512 k] bf16
    const float* __restrict__ bconst,          // [256]
    float* __restrict__ out)                   // [4096][256]
{
    __shared__ __align__(16) unsigned short As[16*512];   // 16 KB, swizzled
    const int m0  = blockIdx.x * 16;
    const int tid = threadIdx.x;
    const int w = tid >> 6, l = tid & 63, lrow = l & 15, lk = l >> 4;

    {   // stage A: k<256 from g2, k>=256 from qe (cvt f32->bf16)
        int row = tid >> 4, lane16 = tid & 15;
        const unsigned short* gp = g2 + (size_t)(m0 + row)*256;
        const float* qp = qe + (size_t)(m0 + row)*256;
        char* dst = (char*)(As + row*512);
        #pragma unroll
        for (int s = 0; s < 2; s++){
            int kb = lane16*32 + s*16;
            int4 v = *reinterpret_cast<const int4*>((const char*)gp + kb);
            *reinterpret_cast<int4*>(dst + (kb ^ ((row & 7) << 4))) = v;
        }
        #pragma unroll
        for (int s = 0; s < 2; s++){
            union { unsigned short u[8]; int4 t; } cu;
            #pragma unroll
            for (int uu = 0; uu < 8; uu++) cu.u[uu] = f2bf(qp[lane16*16 + s*8 + uu]);
            int kb = 512 + lane16*32 + s*16;
            *reinterpret_cast<int4*>(dst + (kb ^ ((row & 7) << 4))) = cu.t;
        }
    }
    __syncthreads();

    f32x4 acc0 = {0.f,0.f,0.f,0.f};
    f32x4 acc1 = {0.f,0.f,0.f,0.f};
    f32x4 acc2 = {0.f,0.f,0.f,0.f};
    f32x4 acc3 = {0.f,0.f,0.f,0.f};
    const unsigned short* Bp = WgT2 + (size_t)(w*64 + lrow)*512 + lk*8;
    const char* Ab = (const char*)(As + lrow*512);
    const int asw = (lrow & 7) << 4;

    #pragma unroll
    for (int k0 = 0; k0 < 512; k0 += 32){
        bf16x8 a  = *reinterpret_cast<const bf16x8*>(Ab + (((k0 + lk*8)*2) ^ asw));
        bf16x8 b0 = *reinterpret_cast<const bf16x8*>(Bp + k0);
        bf16x8 b1 = *reinterpret_cast<const bf16x8*>(Bp + 16*512 + k0);
        bf16x8 b2 = *reinterpret_cast<const bf16x8*>(Bp + 32*512 + k0);
        bf16x8 b3 = *reinterpret_cast<const bf16x8*>(Bp + 48*512 + k0);
        acc0 = __builtin_amdgcn_mfma_f32_16x16x32_bf16(a, b0, acc0, 0, 0, 0);
        acc1 = __builtin_amdgcn_mfma_f32_16x16x32_bf16(a, b1, acc1, 0, 0, 0);
        acc2 = __builtin_amdgcn_mfma_f32_16x16x32_bf16(a, b2, acc2, 0, 0, 0);
        acc3 = __builtin_amdgcn_mfma_f32_16x16x32_bf16(a, b3, acc3, 0, 0, 0);
    }

    const f32x4 accs[4] = {acc0, acc1, acc2, acc3};
    #pragma unroll
    for (int nt = 0; nt < 4; nt++){
        int c = w*64 + nt*16 + lrow;
        float bcv = bconst[c];
        #pragma unroll
        for (int i = 0; i < 4; i++){
            int r = m0 + lk*4 + i;
            out[(size_t)r*256 + c] = accs[nt][i] + bcv;
        }
    }
}

extern "C" void kernel_launch(void* const* d_in, const int* in_sizes, int n_in,
                              void* d_out, int out_size, void* d_ws, size_t ws_size,
                              hipStream_t stream)
{
    (void)in_sizes; (void)n_in; (void)out_size; (void)ws_size;
    float* out = (float*)d_out;
    char*  ws  = (char*)d_ws;

    // workspace layout (ws_size proven >= 102.1 MB by rounds 2-4 haveT executions)
    const size_t OF_CO   = 0;                                  // coords 4096*8*64B
    const size_t OF_WGT2 = OF_CO   + (size_t)4096*8*64;        //  2,097,152
    const size_t OF_WQOA = OF_WGT2 + (size_t)256*512*2;        //  2,359,296
    const size_t OF_BQOA = OF_WQOA + (size_t)256*96*4;         //  2,457,600
    const size_t OF_BC   = OF_BQOA + 512;                      //  2,458,112
    const size_t OF_WVT  = OF_BC   + 1024;                     //  2,459,136
    const size_t OF_G2   = OF_WVT  + (size_t)256*256*2;        //  2,590,208
    const size_t OF_VAL  = OF_G2   + (size_t)4096*256*2;       //  4,687,360
    // NEED = OF_VAL + 4*40000*256*2 = 86,607,360

    float*          coords = (float*)(ws + OF_CO);
    unsigned short* WgT2   = (unsigned short*)(ws + OF_WGT2);
    float*          Wqoa   = (float*)(ws + OF_WQOA);
    float*          bqoa   = (float*)(ws + OF_BQOA);
    float*          bconst = (float*)(ws + OF_BC);
    unsigned short* WvalT  = (unsigned short*)(ws + OF_WVT);
    unsigned short* g2     = (unsigned short*)(ws + OF_G2);
    unsigned short* value  = (unsigned short*)(ws + OF_VAL);

    const float* qe    = (const float*)d_in[0];
    const float* ctrl  = (const float*)d_in[1];
    const float* bev   = (const float*)d_in[2];
    const float* pc    = (const float*)d_in[4];
    const float* Wq    = (const float*)d_in[5];
    const float* bq    = (const float*)d_in[6];
    const float* Wval  = (const float*)d_in[7];
    const float* bval  = (const float*)d_in[8];
    const float* Woff  = (const float*)d_in[9];
    const float* boff  = (const float*)d_in[10];
    const float* Wattn = (const float*)d_in[11];
    const float* battn = (const float*)d_in[12];
    const float* Wdo   = (const float*)d_in[13];
    const float* bdo   = (const float*)d_in[14];
    const float* Wout  = (const float*)d_in[15];
    const float* bout  = (const float*)d_in[16];

    // K0: weight-only prep
    prep_kernel<<<41, 256, 0, stream>>>(Wq, bq, Wval, Woff, boff, Wattn, battn,
                                        Wdo, bdo, Wout, bout,
                                        WgT2, Wqoa, bqoa, bconst, WvalT);
    // K1: value precompute (MFMA) + oa/coords
    valoa_kernel<<<1316, 256, 0, stream>>>(bev, WvalT, bval, qe, ctrl, pc,
                                           Wqoa, bqoa, value, coords);
    // K2: gather (1KB per (m,h), value L3-resident)
    gather2_kernel<<<512, 256, 0, stream>>>(value, coords, g2);
    // K3: fused back-end GEMM
    final2_kernel<<<256, 256, 0, stream>>>(g2, qe, WgT2, bconst, out);
}

// Round 7
// 407.056 us; speedup vs baseline: 1.1555x; 1.0270x over previous
//
#include <hip/hip_runtime.h>

#define BB 4
#define NN 1024
#define DD 256
#define NHEADS 8
#define NPTS 4
#define NKSAMP 10
#define HHF 200
#define WWF 200
#define HWF (HHF*WWF)

typedef __attribute__((ext_vector_type(8))) short bf16x8;
typedef __attribute__((ext_vector_type(4))) float f32x4;

__device__ __forceinline__ unsigned short f2bf(float f){
    unsigned u = __float_as_uint(f);
    return (unsigned short)((u + 0x7FFFu + ((u >> 16) & 1u)) >> 16);
}
__device__ __forceinline__ void load_bf16x8(const unsigned short* p, float* v){
    int4 t = *reinterpret_cast<const int4*>(p);
    unsigned q0 = (unsigned)t.x, q1 = (unsigned)t.y, q2 = (unsigned)t.z, q3 = (unsigned)t.w;
    v[0] = __uint_as_float(q0 << 16); v[1] = __uint_as_float(q0 & 0xFFFF0000u);
    v[2] = __uint_as_float(q1 << 16); v[3] = __uint_as_float(q1 & 0xFFFF0000u);
    v[4] = __uint_as_float(q2 << 16); v[5] = __uint_as_float(q2 & 0xFFFF0000u);
    v[6] = __uint_as_float(q3 << 16); v[7] = __uint_as_float(q3 & 0xFFFF0000u);
}
__device__ __forceinline__ void store_bf16x8(unsigned short* p, const float* v){
    int4 t;
    t.x = (int)((unsigned)f2bf(v[0]) | ((unsigned)f2bf(v[1]) << 16));
    t.y = (int)((unsigned)f2bf(v[2]) | ((unsigned)f2bf(v[3]) << 16));
    t.z = (int)((unsigned)f2bf(v[4]) | ((unsigned)f2bf(v[5]) << 16));
    t.w = (int)((unsigned)f2bf(v[6]) | ((unsigned)f2bf(v[7]) << 16));
    *reinterpret_cast<int4*>(p) = t;
}

// ================== K0: prep — weight-only algebra (37 blocks) ==================
// blocks 0..15 : WgT2[n][k]     = (Wdo@Wout)^T  (k<256)
// blocks 16..31: WgT2[n][256+k] = (Wq @Wout)^T
// block  32    : bconst[n] = (bdo+bq)@Wout + bout
// blocks 33..36: WvalT[n][c] = Wval^T (bf16)
__global__ __launch_bounds__(256) void prep_kernel(
    const float* __restrict__ Wq,   const float* __restrict__ bq,
    const float* __restrict__ Wval,
    const float* __restrict__ Wdo,  const float* __restrict__ bdo,
    const float* __restrict__ Wout, const float* __restrict__ bout,
    unsigned short* __restrict__ WgT2,
    float* __restrict__ bconst,
    unsigned short* __restrict__ WvalT)
{
    __shared__ __align__(16) char smem[33280];
    const int bx = blockIdx.x, tid = threadIdx.x;

    if (bx < 32){
        const float* W  = (bx < 16) ? Wdo : Wq;
        const int dstoff = (bx < 16) ? 0 : 256;
        const int idx2 = bx & 15;
        const int n0 = (idx2 >> 2) * 64;
        const int k0 = (idx2 & 3) * 64;
        float (*WoutS)[64] = (float(*)[64])smem;                 // [64][64]
        float (*WS)[65]    = (float(*)[65])(smem + 64*64*4);     // [64][65]
        const int lc  = tid & 63;
        const int grp = tid >> 6;
        float acc[16];
        #pragma unroll
        for (int u = 0; u < 16; u++) acc[u] = 0.f;
        for (int p = 0; p < 4; p++){
            if (p) __syncthreads();
            #pragma unroll
            for (int i = 0; i < 4; i++){
                int idx = tid + i*256;
                int r = idx >> 4, c4 = (idx & 15)*4;
                *reinterpret_cast<float4*>(&WoutS[r][c4]) =
                    *reinterpret_cast<const float4*>(Wout + (size_t)(p*64 + r)*256 + n0 + c4);
                float4 wv = *reinterpret_cast<const float4*>(W + (size_t)(k0 + r)*256 + p*64 + c4);
                WS[r][c4+0]=wv.x; WS[r][c4+1]=wv.y; WS[r][c4+2]=wv.z; WS[r][c4+3]=wv.w;
            }
            __syncthreads();
            for (int jj = 0; jj < 64; jj++){
                float wq = WS[lc][jj];
                #pragma unroll
                for (int u4 = 0; u4 < 4; u4++){
                    float4 w = *reinterpret_cast<const float4*>(&WoutS[jj][grp*16 + u4*4]);
                    acc[u4*4+0] += wq*w.x; acc[u4*4+1] += wq*w.y;
                    acc[u4*4+2] += wq*w.z; acc[u4*4+3] += wq*w.w;
                }
            }
        }
        #pragma unroll
        for (int u = 0; u < 16; u++)
            WgT2[(size_t)(n0 + grp*16 + u)*512 + dstoff + k0 + lc] = f2bf(acc[u]);
    } else if (bx == 32){
        float s = 0.f;
        for (int k = 0; k < 256; k++) s += (bdo[k] + bq[k]) * Wout[(size_t)k*256 + tid];
        bconst[tid] = s + bout[tid];
    } else {
        // WvalT slab: n0 = (bx-33)*64 ; LDS-transpose 64x64 tiles
        const int n0 = (bx - 33) * 64;
        float (*T)[67] = (float(*)[67])smem;                     // [64 n][67]
        const int tx = tid & 15, ty = tid >> 4;
        for (int ct = 0; ct < 4; ct++){
            if (ct) __syncthreads();
            #pragma unroll
            for (int q = 0; q < 4; q++){
                int c = ct*64 + q*16 + ty;
                float4 v = *reinterpret_cast<const float4*>(Wval + (size_t)c*256 + n0 + tx*4);
                T[tx*4+0][q*16+ty] = v.x; T[tx*4+1][q*16+ty] = v.y;
                T[tx*4+2][q*16+ty] = v.z; T[tx*4+3][q*16+ty] = v.w;
            }
            __syncthreads();
            const int sx = tid & 7, sy = tid >> 3;
            #pragma unroll
            for (int s = 0; s < 2; s++){
                int n = s*32 + sy;
                float v[8];
                #pragma unroll
                for (int u = 0; u < 8; u++) v[u] = T[n][sx*8+u];
                store_bf16x8(WvalT + (size_t)(n0 + n)*256 + ct*64 + sx*8, v);
            }
        }
    }
}

// ================== K1: valoa — value (MFMA, rebuilt) | oa (self-contained) ========
// static LDS 34,816 B.
// blocks [0,64)   : oa role — q=qe@Wq+bq (2x128-k chunks, R3-proven), oa, coords.
// blocks [64,2564): value role — 64-pixel tile:
//   stage: reg-transpose (8 coalesced float4 per thread -> 4 b128 LDS writes),
//          A-panel pixel-major [64][264] bf16 (528B pitch),
//   MFMA : A from LDS b128, B = WvalT from L2, acc[4][4],
//   epi  : D+bval -> bf16 -> swizzled 32KB D-buf (reuses A) -> contiguous b128 stores.
__global__ __launch_bounds__(256) void valoa_kernel(
    const float* __restrict__ bev,
    const unsigned short* __restrict__ WvalT,
    const float* __restrict__ bval,
    const float* __restrict__ qe, const float* __restrict__ ctrl,
    const float* __restrict__ pc,
    const float* __restrict__ Wq,   const float* __restrict__ bq,
    const float* __restrict__ Woff, const float* __restrict__ boff,
    const float* __restrict__ Wattn,const float* __restrict__ battn,
    unsigned short* __restrict__ value,
    float* __restrict__ coords)
{
    __shared__ __align__(16) char smem[34816];
    const int bx = blockIdx.x, tid = threadIdx.x;

    if (bx >= 64){
        // ---------------- value role ----------------
        const int tile = (bx - 64) % 625;
        const int b    = (bx - 64) / 625;
        const int p0   = tile * 64;

        // stage: thread owns pixel-quad pq*4 and channel-octet co*8 (x2 halves)
        {
            const int pq = tid & 15;
            const int co = tid >> 4;          // 0..15
            #pragma unroll
            for (int ch = 0; ch < 2; ch++){
                int c8 = ch*128 + co*8;
                float vals[4][8];
                #pragma unroll
                for (int e = 0; e < 8; e++){
                    float4 f = *reinterpret_cast<const float4*>(
                        bev + ((size_t)b*DD + c8 + e)*HWF + p0 + pq*4);
                    vals[0][e] = f.x; vals[1][e] = f.y; vals[2][e] = f.z; vals[3][e] = f.w;
                }
                #pragma unroll
                for (int i = 0; i < 4; i++){
                    int pix = pq*4 + i;
                    int4 t;
                    t.x = (int)((unsigned)f2bf(vals[i][0]) | ((unsigned)f2bf(vals[i][1]) << 16));
                    t.y = (int)((unsigned)f2bf(vals[i][2]) | ((unsigned)f2bf(vals[i][3]) << 16));
                    t.z = (int)((unsigned)f2bf(vals[i][4]) | ((unsigned)f2bf(vals[i][5]) << 16));
                    t.w = (int)((unsigned)f2bf(vals[i][6]) | ((unsigned)f2bf(vals[i][7]) << 16));
                    *reinterpret_cast<int4*>(smem + pix*528 + c8*2) = t;
                }
            }
        }
        __syncthreads();

        const int w = tid >> 6, l = tid & 63, lrow = l & 15, lk = l >> 4;
        f32x4 acc[4][4];
        #pragma unroll
        for (int mt = 0; mt < 4; mt++)
            #pragma unroll
            for (int nt = 0; nt < 4; nt++) acc[mt][nt] = (f32x4){0.f,0.f,0.f,0.f};

        #pragma unroll
        for (int k0 = 0; k0 < 256; k0 += 32){
            bf16x8 bfr[4];
            #pragma unroll
            for (int nt = 0; nt < 4; nt++)
                bfr[nt] = *reinterpret_cast<const bf16x8*>(
                    WvalT + (size_t)(w*64 + nt*16 + lrow)*256 + k0 + lk*8);
            #pragma unroll
            for (int mt = 0; mt < 4; mt++){
                bf16x8 a = *reinterpret_cast<const bf16x8*>(
                    smem + (mt*16 + lrow)*528 + (k0 + lk*8)*2);
                acc[mt][0] = __builtin_amdgcn_mfma_f32_16x16x32_bf16(a, bfr[0], acc[mt][0], 0,0,0);
                acc[mt][1] = __builtin_amdgcn_mfma_f32_16x16x32_bf16(a, bfr[1], acc[mt][1], 0,0,0);
                acc[mt][2] = __builtin_amdgcn_mfma_f32_16x16x32_bf16(a, bfr[2], acc[mt][2], 0,0,0);
                acc[mt][3] = __builtin_amdgcn_mfma_f32_16x16x32_bf16(a, bfr[3], acc[mt][3], 0,0,0);
            }
        }
        __syncthreads();                     // A-panel consumed

        // D (+bval) -> D-buf [64 pix][512B], column bytes XOR-swizzled by pixel
        #pragma unroll
        for (int nt = 0; nt < 4; nt++){
            int n = w*64 + nt*16 + lrow;
            float bv = bval[n];
            #pragma unroll
            for (int mt = 0; mt < 4; mt++)
                #pragma unroll
                for (int i = 0; i < 4; i++){
                    int pix = mt*16 + lk*4 + i;
                    int byte = pix*512 + ((n*2) ^ (((pix>>2)&7)<<4));
                    *(unsigned short*)(smem + byte) = f2bf(acc[mt][nt][i] + bv);
                }
        }
        __syncthreads();
        // drain: 2048 x 16B chunks, 32 chunks per 512B pixel row (FIX: >>5/&31)
        unsigned short* vrow = value + ((size_t)b*HWF + p0)*256;
        #pragma unroll
        for (int j = 0; j < 8; j++){
            int chunk = j*256 + tid;
            int pix = chunk >> 5, inner = chunk & 31;
            int byte = pix*512 + ((inner*16) ^ (((pix>>2)&7)<<4));
            int4 v = *reinterpret_cast<const int4*>(smem + byte);
            *reinterpret_cast<int4*>(vrow + (size_t)pix*256 + inner*8) = v;
        }
    } else {
        // ---------------- oa role (R3-proven chunked math) ----------------
        const int m0 = bx * 64;
        float (*As)[68] = (float(*)[68])smem;       // [128 k][68]
        const int ti = tid & 15;
        const int tj = tid >> 4;

        float qreg[16][4];
        #pragma unroll
        for (int t = 0; t < 16; t++){
            float bqv = bq[(t >> 2)*64 + tj*4 + (t & 3)];
            #pragma unroll
            for (int i = 0; i < 4; i++) qreg[t][i] = bqv;
        }
        for (int ck = 0; ck < 2; ck++){
            if (ck) __syncthreads();
            {
                int r  = tid >> 2;
                int kb = (tid & 3) * 4;
                #pragma unroll
                for (int kk = 0; kk < 8; kk++){
                    int k = kb + kk*16;
                    float4 v = *reinterpret_cast<const float4*>(
                        qe + (size_t)(m0 + r)*256 + ck*128 + k);
                    As[k+0][r] = v.x; As[k+1][r] = v.y; As[k+2][r] = v.z; As[k+3][r] = v.w;
                }
            }
            __syncthreads();
            #pragma unroll
            for (int slab = 0; slab < 4; slab++){
                #pragma unroll 4
                for (int c = 0; c < 128; c++){
                    float4 a = *reinterpret_cast<const float4*>(&As[c][ti*4]);
                    float av[4] = {a.x, a.y, a.z, a.w};
                    float4 b = *reinterpret_cast<const float4*>(
                        Wq + (size_t)(ck*128 + c)*256 + slab*64 + tj*4);
                    float bv[4] = {b.x, b.y, b.z, b.w};
                    #pragma unroll
                    for (int i = 0; i < 4; i++){
                        qreg[slab*4+0][i] += av[i]*bv[0];
                        qreg[slab*4+1][i] += av[i]*bv[1];
                        qreg[slab*4+2][i] += av[i]*bv[2];
                        qreg[slab*4+3][i] += av[i]*bv[3];
                    }
                }
            }
        }

        float (*qT)[68] = (float(*)[68])smem;
        float ao[4][4], aa[4][2];
        #pragma unroll
        for (int i = 0; i < 4; i++){
            #pragma unroll
            for (int j = 0; j < 4; j++) ao[i][j] = 0.f;
            aa[i][0] = 0.f; aa[i][1] = 0.f;
        }
        for (int ck = 0; ck < 2; ck++){
            __syncthreads();
            #pragma unroll
            for (int t = ck*8; t < ck*8 + 8; t++){
                int c = ((t >> 2) & 1)*64 + tj*4 + (t & 3);
                #pragma unroll
                for (int i = 0; i < 4; i++) qT[c][ti*4 + i] = qreg[t][i];
            }
            __syncthreads();
            #pragma unroll 4
            for (int c = 0; c < 128; c++){
                float4 a = *reinterpret_cast<const float4*>(&qT[c][ti*4]);
                float av[4] = {a.x, a.y, a.z, a.w};
                float4 bo = *reinterpret_cast<const float4*>(Woff  + (size_t)(ck*128 + c)*64 + tj*4);
                float2 ba = *reinterpret_cast<const float2*>(Wattn + (size_t)(ck*128 + c)*32 + tj*2);
                #pragma unroll
                for (int i = 0; i < 4; i++){
                    ao[i][0] += av[i]*bo.x; ao[i][1] += av[i]*bo.y;
                    ao[i][2] += av[i]*bo.z; ao[i][3] += av[i]*bo.w;
                    aa[i][0] += av[i]*ba.x; aa[i][1] += av[i]*ba.y;
                }
            }
        }
        __syncthreads();
        float* oaS = (float*)smem;       // [64][96]
        #pragma unroll
        for (int i = 0; i < 4; i++){
            int r = ti*4 + i;
            #pragma unroll
            for (int j = 0; j < 4; j++) oaS[r*96 + tj*4 + j] = ao[i][j] + boff[tj*4 + j];
            oaS[r*96 + 64 + tj*2 + 0] = aa[i][0] + battn[tj*2 + 0];
            oaS[r*96 + 64 + tj*2 + 1] = aa[i][1] + battn[tj*2 + 1];
        }
        __syncthreads();

        const float lox = pc[0], loy = pc[1];
        const float spx = pc[3] - lox, spy = pc[4] - loy;
        for (int idx = tid; idx < 512; idx += 256){
            int r = idx >> 3, h = idx & 7;
            int m = m0 + r;
            float cx[4], cy[4];
            #pragma unroll
            for (int i = 0; i < 4; i++){
                cx[i] = ctrl[(size_t)m*8 + i*2 + 0];
                cy[i] = ctrl[(size_t)m*8 + i*2 + 1];
            }
            float sx = 0.f, sy = 0.f;
            for (int k = 0; k < NKSAMP; k++){
                float t = (float)k / (float)(NKSAMP - 1);
                float u = 1.f - t;
                float c0 = u*u*u, c1 = 3.f*u*u*t, c2 = 3.f*u*t*t, c3 = t*t*t;
                float dx = c0*cx[0] + c1*cx[1] + c2*cx[2] + c3*cx[3];
                float dy = c0*cy[0] + c1*cy[1] + c2*cy[2] + c3*cy[3];
                float rx = fminf(fmaxf((dx - lox)/spx, 0.01f), 0.99f);
                float ry = fminf(fmaxf((dy - loy)/spy, 0.01f), 0.99f);
                sx += rx; sy += ry;
            }
            float cxp = (sx / (float)NKSAMP) * (float)WWF - 0.5f;
            float cyp = (sy / (float)NKSAMP) * (float)HHF - 0.5f;

            const float* row = oaS + r*96;
            float a0 = row[64 + h*4 + 0], a1 = row[64 + h*4 + 1];
            float a2 = row[64 + h*4 + 2], a3 = row[64 + h*4 + 3];
            float mx = fmaxf(fmaxf(a0, a1), fmaxf(a2, a3));
            float e0 = __expf(a0 - mx), e1 = __expf(a1 - mx);
            float e2 = __expf(a2 - mx), e3 = __expf(a3 - mx);
            float inv = 1.f / (e0 + e1 + e2 + e3);
            float wp[4] = {e0*inv, e1*inv, e2*inv, e3*inv};
            float* cp = coords + ((size_t)m*8 + h)*16;
            #pragma unroll
            for (int p = 0; p < 4; p++){
                cp[p*4 + 0] = cxp + row[h*8 + p*2 + 0];
                cp[p*4 + 1] = cyp + row[h*8 + p*2 + 1];
                cp[p*4 + 2] = wp[p];
                cp[p*4 + 3] = 0.f;
            }
        }
    }
}

// ================== K2: gather — 1KB per (m,h) from value (L3-resident) ============
__global__ __launch_bounds__(256) void gather2_kernel(
    const unsigned short* __restrict__ value,   // (B,HW,256) bf16
    const float* __restrict__ coords,           // per (m,h): 4 x {x,y,w,pad}
    unsigned short* __restrict__ g2)            // [4096][256] bf16
{
    const int pair0 = blockIdx.x * 64;
    const int tid   = threadIdx.x;
    const int slice = tid & 3;                  // 8 channels each
    const int pair  = pair0 + (tid >> 2);
    const int m = pair >> 3, h = pair & 7, b = m >> 10;
    const float* cp = coords + (size_t)pair * 16;

    float acc[8] = {0.f,0.f,0.f,0.f,0.f,0.f,0.f,0.f};
    #pragma unroll
    for (int p = 0; p < 4; p++){
        float4 c4 = *reinterpret_cast<const float4*>(cp + p*4);
        float x = c4.x, y = c4.y, wq = c4.z;
        float fx = floorf(x), fy = floorf(y);
        int x0 = (int)fx, y0 = (int)fy;
        float wx = x - fx, wy = y - fy;
        int   xs[4]  = {x0, x0+1, x0,   x0+1};
        int   ys[4]  = {y0, y0,   y0+1, y0+1};
        float ws4[4] = {wq*(1.f-wx)*(1.f-wy), wq*wx*(1.f-wy), wq*(1.f-wx)*wy, wq*wx*wy};
        #pragma unroll
        for (int ci = 0; ci < 4; ci++){
            int xi = xs[ci], yi = ys[ci];
            if ((unsigned)xi < WWF && (unsigned)yi < HHF){
                const unsigned short* vp =
                    value + ((size_t)b*HWF + yi*WWF + xi)*256 + h*32 + slice*8;
                float v[8]; load_bf16x8(vp, v);
                float wgt = ws4[ci];
                #pragma unroll
                for (int i = 0; i < 8; i++) acc[i] += wgt * v[i];
            }
        }
    }
    store_bf16x8(g2 + (size_t)m*256 + h*32 + slice*8, acc);
}

// ================== K3: final — out = [g2 | bf16(qe)] @ WgT2^T + bconst =============
__global__ __launch_bounds__(256) void final2_kernel(
    const unsigned short* __restrict__ g2,     // [4096][256] bf16
    const float* __restrict__ qe,              // [4096][256] f32
    const unsigned short* __restrict__ WgT2,   // [256 n][512 k] bf16
    const float* __restrict__ bconst,          // [256]
    float* __restrict__ out)                   // [4096][256]
{
    __shared__ __align__(16) unsigned short As[16*512];   // 16 KB, swizzled
    const int m0  = blockIdx.x * 16;
    const int tid = threadIdx.x;
    const int w = tid >> 6, l = tid & 63, lrow = l & 15, lk = l >> 4;

    {   // stage A: k<256 from g2, k>=256 from qe (cvt f32->bf16)
        int row = tid >> 4, lane16 = tid & 15;
        const unsigned short* gp = g2 + (size_t)(m0 + row)*256;
        const float* qp = qe + (size_t)(m0 + row)*256;
        char* dst = (char*)(As + row*512);
        #pragma unroll
        for (int s = 0; s < 2; s++){
            int kb = lane16*32 + s*16;
            int4 v = *reinterpret_cast<const int4*>((const char*)gp + kb);
            *reinterpret_cast<int4*>(dst + (kb ^ ((row & 7) << 4))) = v;
        }
        #pragma unroll
        for (int s = 0; s < 2; s++){
            union { unsigned short u[8]; int4 t; } cu;
            #pragma unroll
            for (int uu = 0; uu < 8; uu++) cu.u[uu] = f2bf(qp[lane16*16 + s*8 + uu]);
            int kb = 512 + lane16*32 + s*16;
            *reinterpret_cast<int4*>(dst + (kb ^ ((row & 7) << 4))) = cu.t;
        }
    }
    __syncthreads();

    f32x4 acc0 = {0.f,0.f,0.f,0.f};
    f32x4 acc1 = {0.f,0.f,0.f,0.f};
    f32x4 acc2 = {0.f,0.f,0.f,0.f};
    f32x4 acc3 = {0.f,0.f,0.f,0.f};
    const unsigned short* Bp = WgT2 + (size_t)(w*64 + lrow)*512 + lk*8;
    const char* Ab = (const char*)(As + lrow*512);
    const int asw = (lrow & 7) << 4;

    #pragma unroll
    for (int k0 = 0; k0 < 512; k0 += 32){
        bf16x8 a  = *reinterpret_cast<const bf16x8*>(Ab + (((k0 + lk*8)*2) ^ asw));
        bf16x8 b0 = *reinterpret_cast<const bf16x8*>(Bp + k0);
        bf16x8 b1 = *reinterpret_cast<const bf16x8*>(Bp + 16*512 + k0);
        bf16x8 b2 = *reinterpret_cast<const bf16x8*>(Bp + 32*512 + k0);
        bf16x8 b3 = *reinterpret_cast<const bf16x8*>(Bp + 48*512 + k0);
        acc0 = __builtin_amdgcn_mfma_f32_16x16x32_bf16(a, b0, acc0, 0, 0, 0);
        acc1 = __builtin_amdgcn_mfma_f32_16x16x32_bf16(a, b1, acc1, 0, 0, 0);
        acc2 = __builtin_amdgcn_mfma_f32_16x16x32_bf16(a, b2, acc2, 0, 0, 0);
        acc3 = __builtin_amdgcn_mfma_f32_16x16x32_bf16(a, b3, acc3, 0, 0, 0);
    }

    const f32x4 accs[4] = {acc0, acc1, acc2, acc3};
    #pragma unroll
    for (int nt = 0; nt < 4; nt++){
        int c = w*64 + nt*16 + lrow;
        float bcv = bconst[c];
        #pragma unroll
        for (int i = 0; i < 4; i++){
            int r = m0 + lk*4 + i;
            out[(size_t)r*256 + c] = accs[nt][i] + bcv;
        }
    }
}

extern "C" void kernel_launch(void* const* d_in, const int* in_sizes, int n_in,
                              void* d_out, int out_size, void* d_ws, size_t ws_size,
                              hipStream_t stream)
{
    (void)in_sizes; (void)n_in; (void)out_size; (void)ws_size;
    float* out = (float*)d_out;
    char*  ws  = (char*)d_ws;

    const size_t OF_CO   = 0;                                  // coords 4096*8*64B
    const size_t OF_WGT2 = OF_CO   + (size_t)4096*8*64;        //  2,097,152
    const size_t OF_BC   = OF_WGT2 + (size_t)256*512*2;        //  2,359,296
    const size_t OF_WVT  = OF_BC   + 1024;                     //  2,360,320
    const size_t OF_G2   = OF_WVT  + (size_t)256*256*2;        //  2,491,392
    const size_t OF_VAL  = OF_G2   + (size_t)4096*256*2;       //  4,588,544
    // NEED = OF_VAL + 4*40000*256*2 = 86,508,544 (ws proven >= 102.1 MB in R2-R4)

    float*          coords = (float*)(ws + OF_CO);
    unsigned short* WgT2   = (unsigned short*)(ws + OF_WGT2);
    float*          bconst = (float*)(ws + OF_BC);
    unsigned short* WvalT  = (unsigned short*)(ws + OF_WVT);
    unsigned short* g2     = (unsigned short*)(ws + OF_G2);
    unsigned short* value  = (unsigned short*)(ws + OF_VAL);

    const float* qe    = (const float*)d_in[0];
    const float* ctrl  = (const float*)d_in[1];
    const float* bev   = (const float*)d_in[2];
    const float* pc    = (const float*)d_in[4];
    const float* Wq    = (const float*)d_in[5];
    const float* bq    = (const float*)d_in[6];
    const float* Wval  = (const float*)d_in[7];
    const float* bval  = (const float*)d_in[8];
    const float* Woff  = (const float*)d_in[9];
    const float* boff  = (const float*)d_in[10];
    const float* Wattn = (const float*)d_in[11];
    const float* battn = (const float*)d_in[12];
    const float* Wdo   = (const float*)d_in[13];
    const float* bdo   = (const float*)d_in[14];
    const float* Wout  = (const float*)d_in[15];
    const float* bout  = (const float*)d_in[16];

    // K0: weight-only prep (WgT2, bconst, WvalT)
    prep_kernel<<<37, 256, 0, stream>>>(Wq, bq, Wval, Wdo, bdo, Wout, bout,
                                        WgT2, bconst, WvalT);
    // K1: value precompute (rebuilt) + self-contained oa
    valoa_kernel<<<2564, 256, 0, stream>>>(bev, WvalT, bval, qe, ctrl, pc,
                                           Wq, bq, Woff, boff, Wattn, battn,
                                           value, coords);
    // K2: gather (1KB per (m,h))
    gather2_kernel<<<512, 256, 0, stream>>>(value, coords, g2);
    // K3: fused back-end GEMM
    final2_kernel<<<256, 256, 0, stream>>>(g2, qe, WgT2, bconst, out);
}

// Round 8
// 394.359 us; speedup vs baseline: 1.1927x; 1.0322x over previous
//
#include <hip/hip_runtime.h>

#define BB 4
#define NN 1024
#define DD 256
#define NHEADS 8
#define NPTS 4
#define NKSAMP 10
#define HHF 200
#define WWF 200
#define HWF (HHF*WWF)

typedef __attribute__((ext_vector_type(8))) short bf16x8;
typedef __attribute__((ext_vector_type(4))) float f32x4;

__device__ __forceinline__ unsigned short f2bf(float f){
    unsigned u = __float_as_uint(f);
    return (unsigned short)((u + 0x7FFFu + ((u >> 16) & 1u)) >> 16);
}
__device__ __forceinline__ void load_bf16x8(const unsigned short* p, float* v){
    int4 t = *reinterpret_cast<const int4*>(p);
    unsigned q0 = (unsigned)t.x, q1 = (unsigned)t.y, q2 = (unsigned)t.z, q3 = (unsigned)t.w;
    v[0] = __uint_as_float(q0 << 16); v[1] = __uint_as_float(q0 & 0xFFFF0000u);
    v[2] = __uint_as_float(q1 << 16); v[3] = __uint_as_float(q1 & 0xFFFF0000u);
    v[4] = __uint_as_float(q2 << 16); v[5] = __uint_as_float(q2 & 0xFFFF0000u);
    v[6] = __uint_as_float(q3 << 16); v[7] = __uint_as_float(q3 & 0xFFFF0000u);
}
__device__ __forceinline__ void store_bf16x8(unsigned short* p, const float* v){
    int4 t;
    t.x = (int)((unsigned)f2bf(v[0]) | ((unsigned)f2bf(v[1]) << 16));
    t.y = (int)((unsigned)f2bf(v[2]) | ((unsigned)f2bf(v[3]) << 16));
    t.z = (int)((unsigned)f2bf(v[4]) | ((unsigned)f2bf(v[5]) << 16));
    t.w = (int)((unsigned)f2bf(v[6]) | ((unsigned)f2bf(v[7]) << 16));
    *reinterpret_cast<int4*>(p) = t;
}

// ================== K0: prep — weight-only algebra (37 blocks) ==================
__global__ __launch_bounds__(256) void prep_kernel(
    const float* __restrict__ Wq,   const float* __restrict__ bq,
    const float* __restrict__ Wval,
    const float* __restrict__ Wdo,  const float* __restrict__ bdo,
    const float* __restrict__ Wout, const float* __restrict__ bout,
    unsigned short* __restrict__ WgT2,
    float* __restrict__ bconst,
    unsigned short* __restrict__ WvalT)
{
    __shared__ __align__(16) char smem[33280];
    const int bx = blockIdx.x, tid = threadIdx.x;

    if (bx < 32){
        const float* W  = (bx < 16) ? Wdo : Wq;
        const int dstoff = (bx < 16) ? 0 : 256;
        const int idx2 = bx & 15;
        const int n0 = (idx2 >> 2) * 64;
        const int k0 = (idx2 & 3) * 64;
        float (*WoutS)[64] = (float(*)[64])smem;                 // [64][64]
        float (*WS)[65]    = (float(*)[65])(smem + 64*64*4);     // [64][65]
        const int lc  = tid & 63;
        const int grp = tid >> 6;
        float acc[16];
        #pragma unroll
        for (int u = 0; u < 16; u++) acc[u] = 0.f;
        for (int p = 0; p < 4; p++){
            if (p) __syncthreads();
            #pragma unroll
            for (int i = 0; i < 4; i++){
                int idx = tid + i*256;
                int r = idx >> 4, c4 = (idx & 15)*4;
                *reinterpret_cast<float4*>(&WoutS[r][c4]) =
                    *reinterpret_cast<const float4*>(Wout + (size_t)(p*64 + r)*256 + n0 + c4);
                float4 wv = *reinterpret_cast<const float4*>(W + (size_t)(k0 + r)*256 + p*64 + c4);
                WS[r][c4+0]=wv.x; WS[r][c4+1]=wv.y; WS[r][c4+2]=wv.z; WS[r][c4+3]=wv.w;
            }
            __syncthreads();
            for (int jj = 0; jj < 64; jj++){
                float wq = WS[lc][jj];
                #pragma unroll
                for (int u4 = 0; u4 < 4; u4++){
                    float4 w = *reinterpret_cast<const float4*>(&WoutS[jj][grp*16 + u4*4]);
                    acc[u4*4+0] += wq*w.x; acc[u4*4+1] += wq*w.y;
                    acc[u4*4+2] += wq*w.z; acc[u4*4+3] += wq*w.w;
                }
            }
        }
        #pragma unroll
        for (int u = 0; u < 16; u++)
            WgT2[(size_t)(n0 + grp*16 + u)*512 + dstoff + k0 + lc] = f2bf(acc[u]);
    } else if (bx == 32){
        float s = 0.f;
        for (int k = 0; k < 256; k++) s += (bdo[k] + bq[k]) * Wout[(size_t)k*256 + tid];
        bconst[tid] = s + bout[tid];
    } else {
        // WvalT slab: n0 = (bx-33)*64 ; LDS-transpose 64x64 tiles
        const int n0 = (bx - 33) * 64;
        float (*T)[67] = (float(*)[67])smem;                     // [64 n][67]
        const int tx = tid & 15, ty = tid >> 4;
        for (int ct = 0; ct < 4; ct++){
            if (ct) __syncthreads();
            #pragma unroll
            for (int q = 0; q < 4; q++){
                int c = ct*64 + q*16 + ty;
                float4 v = *reinterpret_cast<const float4*>(Wval + (size_t)c*256 + n0 + tx*4);
                T[tx*4+0][q*16+ty] = v.x; T[tx*4+1][q*16+ty] = v.y;
                T[tx*4+2][q*16+ty] = v.z; T[tx*4+3][q*16+ty] = v.w;
            }
            __syncthreads();
            const int sx = tid & 7, sy = tid >> 3;
            #pragma unroll
            for (int s = 0; s < 2; s++){
                int n = s*32 + sy;
                float v[8];
                #pragma unroll
                for (int u = 0; u < 8; u++) v[u] = T[n][sx*8+u];
                store_bf16x8(WvalT + (size_t)(n0 + n)*256 + ct*64 + sx*8, v);
            }
        }
    }
}

// ================== K1: valoa — value (512-B granular reads) | oa ==================
// static LDS 67,584 B -> 2 blocks/CU.
// blocks [0,64)   : oa role — unchanged (R3/R7-proven).
// blocks [64,1316): value role — 128-pixel tile:
//   stage: wave-wide channel-PAIR loads (one instr = 2 x 512B contiguous segments),
//          transpose via scalar b16 writes into A-panel [128][264] bf16, pitch 528,
//          XOR-16B swizzle keyed by (p>>3)&7 (~4-way worst, write side).
//   MFMA : per wave 64 out-ch x 8 m-tiles, acc[8][4]; B = WvalT (L2-hot).
//   epi  : D+bval -> D-buf (reuses A, swz (pix>>2)&7) -> contiguous b128 drain.
__global__ __launch_bounds__(256) void valoa_kernel(
    const float* __restrict__ bev,
    const unsigned short* __restrict__ WvalT,
    const float* __restrict__ bval,
    const float* __restrict__ qe, const float* __restrict__ ctrl,
    const float* __restrict__ pc,
    const float* __restrict__ Wq,   const float* __restrict__ bq,
    const float* __restrict__ Woff, const float* __restrict__ boff,
    const float* __restrict__ Wattn,const float* __restrict__ battn,
    unsigned short* __restrict__ value,
    float* __restrict__ coords)
{
    __shared__ __align__(16) char smem[67584];
    const int bx = blockIdx.x, tid = threadIdx.x;

    if (bx >= 64){
        // ---------------- value role ----------------
        const int vb   = bx - 64;
        const int tile = vb % 313;
        const int b    = vb / 313;
        int p0 = tile * 128;
        if (p0 > HWF - 128) p0 = HWF - 128;    // tail: overlap-write identical data

        const int lane = tid & 63, wv = tid >> 6;
        {   // stage: 32 iterations, each = one wave-wide 2-channel load (2x512B)
            const int half = lane >> 5;        // channel parity within pair
            const int l5   = lane & 31;        // pixel quad index
            #pragma unroll 8
            for (int it = 0; it < 32; it++){
                int c = wv*64 + it*2 + half;
                float4 f = *reinterpret_cast<const float4*>(
                    bev + ((size_t)b*DD + c)*HWF + p0 + l5*4);
                float fv[4] = {f.x, f.y, f.z, f.w};
                #pragma unroll
                for (int j = 0; j < 4; j++){
                    int p = l5*4 + j;
                    int byte = p*528 + ((c*2) ^ (((p>>3)&7)<<4));
                    *(unsigned short*)(smem + byte) = f2bf(fv[j]);
                }
            }
        }
        __syncthreads();

        const int lrow = lane & 15, lk = lane >> 4;
        f32x4 acc[8][4];
        #pragma unroll
        for (int mt = 0; mt < 8; mt++)
            #pragma unroll
            for (int nt = 0; nt < 4; nt++) acc[mt][nt] = (f32x4){0.f,0.f,0.f,0.f};

        #pragma unroll
        for (int k0 = 0; k0 < 256; k0 += 32){
            bf16x8 bfr[4];
            #pragma unroll
            for (int nt = 0; nt < 4; nt++)
                bfr[nt] = *reinterpret_cast<const bf16x8*>(
                    WvalT + (size_t)(wv*64 + nt*16 + lrow)*256 + k0 + lk*8);
            #pragma unroll
            for (int mt = 0; mt < 8; mt++){
                int pix = mt*16 + lrow;
                int byte = pix*528 + (((k0 + lk*8)*2) ^ (((pix>>3)&7)<<4));
                bf16x8 a = *reinterpret_cast<const bf16x8*>(smem + byte);
                acc[mt][0] = __builtin_amdgcn_mfma_f32_16x16x32_bf16(a, bfr[0], acc[mt][0], 0,0,0);
                acc[mt][1] = __builtin_amdgcn_mfma_f32_16x16x32_bf16(a, bfr[1], acc[mt][1], 0,0,0);
                acc[mt][2] = __builtin_amdgcn_mfma_f32_16x16x32_bf16(a, bfr[2], acc[mt][2], 0,0,0);
                acc[mt][3] = __builtin_amdgcn_mfma_f32_16x16x32_bf16(a, bfr[3], acc[mt][3], 0,0,0);
            }
        }
        __syncthreads();                     // A-panel consumed

        // D (+bval) -> D-buf [128 pix][pitch 528], column bytes XOR by (pix>>2)&7
        #pragma unroll
        for (int nt = 0; nt < 4; nt++){
            int n = wv*64 + nt*16 + lrow;
            float bv = bval[n];
            #pragma unroll
            for (int mt = 0; mt < 8; mt++)
                #pragma unroll
                for (int i = 0; i < 4; i++){
                    int pix = mt*16 + lk*4 + i;
                    int byte = pix*528 + ((n*2) ^ (((pix>>2)&7)<<4));
                    *(unsigned short*)(smem + byte) = f2bf(acc[mt][nt][i] + bv);
                }
        }
        __syncthreads();
        // drain: 4096 x 16B chunks, 32 per 512B pixel row; contiguous global writes
        unsigned short* vrow = value + ((size_t)b*HWF + p0)*256;
        #pragma unroll
        for (int j = 0; j < 16; j++){
            int chunk = j*256 + tid;
            int pix = chunk >> 5, inner = chunk & 31;
            int byte = pix*528 + ((inner*16) ^ (((pix>>2)&7)<<4));
            int4 v = *reinterpret_cast<const int4*>(smem + byte);
            *reinterpret_cast<int4*>(vrow + (size_t)pix*256 + inner*8) = v;
        }
    } else {
        // ---------------- oa role (R3/R7-proven, unchanged) ----------------
        const int m0 = bx * 64;
        float (*As)[68] = (float(*)[68])smem;       // [128 k][68]
        const int ti = tid & 15;
        const int tj = tid >> 4;

        float qreg[16][4];
        #pragma unroll
        for (int t = 0; t < 16; t++){
            float bqv = bq[(t >> 2)*64 + tj*4 + (t & 3)];
            #pragma unroll
            for (int i = 0; i < 4; i++) qreg[t][i] = bqv;
        }
        for (int ck = 0; ck < 2; ck++){
            if (ck) __syncthreads();
            {
                int r  = tid >> 2;
                int kb = (tid & 3) * 4;
                #pragma unroll
                for (int kk = 0; kk < 8; kk++){
                    int k = kb + kk*16;
                    float4 v = *reinterpret_cast<const float4*>(
                        qe + (size_t)(m0 + r)*256 + ck*128 + k);
                    As[k+0][r] = v.x; As[k+1][r] = v.y; As[k+2][r] = v.z; As[k+3][r] = v.w;
                }
            }
            __syncthreads();
            #pragma unroll
            for (int slab = 0; slab < 4; slab++){
                #pragma unroll 4
                for (int c = 0; c < 128; c++){
                    float4 a = *reinterpret_cast<const float4*>(&As[c][ti*4]);
                    float av[4] = {a.x, a.y, a.z, a.w};
                    float4 b = *reinterpret_cast<const float4*>(
                        Wq + (size_t)(ck*128 + c)*256 + slab*64 + tj*4);
                    float bv[4] = {b.x, b.y, b.z, b.w};
                    #pragma unroll
                    for (int i = 0; i < 4; i++){
                        qreg[slab*4+0][i] += av[i]*bv[0];
                        qreg[slab*4+1][i] += av[i]*bv[1];
                        qreg[slab*4+2][i] += av[i]*bv[2];
                        qreg[slab*4+3][i] += av[i]*bv[3];
                    }
                }
            }
        }

        float (*qT)[68] = (float(*)[68])smem;
        float ao[4][4], aa[4][2];
        #pragma unroll
        for (int i = 0; i < 4; i++){
            #pragma unroll
            for (int j = 0; j < 4; j++) ao[i][j] = 0.f;
            aa[i][0] = 0.f; aa[i][1] = 0.f;
        }
        for (int ck = 0; ck < 2; ck++){
            __syncthreads();
            #pragma unroll
            for (int t = ck*8; t < ck*8 + 8; t++){
                int c = ((t >> 2) & 1)*64 + tj*4 + (t & 3);
                #pragma unroll
                for (int i = 0; i < 4; i++) qT[c][ti*4 + i] = qreg[t][i];
            }
            __syncthreads();
            #pragma unroll 4
            for (int c = 0; c < 128; c++){
                float4 a = *reinterpret_cast<const float4*>(&qT[c][ti*4]);
                float av[4] = {a.x, a.y, a.z, a.w};
                float4 bo = *reinterpret_cast<const float4*>(Woff  + (size_t)(ck*128 + c)*64 + tj*4);
                float2 ba = *reinterpret_cast<const float2*>(Wattn + (size_t)(ck*128 + c)*32 + tj*2);
                #pragma unroll
                for (int i = 0; i < 4; i++){
                    ao[i][0] += av[i]*bo.x; ao[i][1] += av[i]*bo.y;
                    ao[i][2] += av[i]*bo.z; ao[i][3] += av[i]*bo.w;
                    aa[i][0] += av[i]*ba.x; aa[i][1] += av[i]*ba.y;
                }
            }
        }
        __syncthreads();
        float* oaS = (float*)smem;       // [64][96]
        #pragma unroll
        for (int i = 0; i < 4; i++){
            int r = ti*4 + i;
            #pragma unroll
            for (int j = 0; j < 4; j++) oaS[r*96 + tj*4 + j] = ao[i][j] + boff[tj*4 + j];
            oaS[r*96 + 64 + tj*2 + 0] = aa[i][0] + battn[tj*2 + 0];
            oaS[r*96 + 64 + tj*2 + 1] = aa[i][1] + battn[tj*2 + 1];
        }
        __syncthreads();

        const float lox = pc[0], loy = pc[1];
        const float spx = pc[3] - lox, spy = pc[4] - loy;
        for (int idx = tid; idx < 512; idx += 256){
            int r = idx >> 3, h = idx & 7;
            int m = m0 + r;
            float cx[4], cy[4];
            #pragma unroll
            for (int i = 0; i < 4; i++){
                cx[i] = ctrl[(size_t)m*8 + i*2 + 0];
                cy[i] = ctrl[(size_t)m*8 + i*2 + 1];
            }
            float sx = 0.f, sy = 0.f;
            for (int k = 0; k < NKSAMP; k++){
                float t = (float)k / (float)(NKSAMP - 1);
                float u = 1.f - t;
                float c0 = u*u*u, c1 = 3.f*u*u*t, c2 = 3.f*u*t*t, c3 = t*t*t;
                float dx = c0*cx[0] + c1*cx[1] + c2*cx[2] + c3*cx[3];
                float dy = c0*cy[0] + c1*cy[1] + c2*cy[2] + c3*cy[3];
                float rx = fminf(fmaxf((dx - lox)/spx, 0.01f), 0.99f);
                float ry = fminf(fmaxf((dy - loy)/spy, 0.01f), 0.99f);
                sx += rx; sy += ry;
            }
            float cxp = (sx / (float)NKSAMP) * (float)WWF - 0.5f;
            float cyp = (sy / (float)NKSAMP) * (float)HHF - 0.5f;

            const float* row = oaS + r*96;
            float a0 = row[64 + h*4 + 0], a1 = row[64 + h*4 + 1];
            float a2 = row[64 + h*4 + 2], a3 = row[64 + h*4 + 3];
            float mx = fmaxf(fmaxf(a0, a1), fmaxf(a2, a3));
            float e0 = __expf(a0 - mx), e1 = __expf(a1 - mx);
            float e2 = __expf(a2 - mx), e3 = __expf(a3 - mx);
            float inv = 1.f / (e0 + e1 + e2 + e3);
            float wp[4] = {e0*inv, e1*inv, e2*inv, e3*inv};
            float* cp = coords + ((size_t)m*8 + h)*16;
            #pragma unroll
            for (int p = 0; p < 4; p++){
                cp[p*4 + 0] = cxp + row[h*8 + p*2 + 0];
                cp[p*4 + 1] = cyp + row[h*8 + p*2 + 1];
                cp[p*4 + 2] = wp[p];
                cp[p*4 + 3] = 0.f;
            }
        }
    }
}

// ================== K2: gather — 1KB per (m,h) from value ============
__global__ __launch_bounds__(256) void gather2_kernel(
    const unsigned short* __restrict__ value,   // (B,HW,256) bf16
    const float* __restrict__ coords,           // per (m,h): 4 x {x,y,w,pad}
    unsigned short* __restrict__ g2)            // [4096][256] bf16
{
    const int pair0 = blockIdx.x * 64;
    const int tid   = threadIdx.x;
    const int slice = tid & 3;                  // 8 channels each
    const int pair  = pair0 + (tid >> 2);
    const int m = pair >> 3, h = pair & 7, b = m >> 10;
    const float* cp = coords + (size_t)pair * 16;

    float acc[8] = {0.f,0.f,0.f,0.f,0.f,0.f,0.f,0.f};
    #pragma unroll
    for (int p = 0; p < 4; p++){
        float4 c4 = *reinterpret_cast<const float4*>(cp + p*4);
        float x = c4.x, y = c4.y, wq = c4.z;
        float fx = floorf(x), fy = floorf(y);
        int x0 = (int)fx, y0 = (int)fy;
        float wx = x - fx, wy = y - fy;
        int   xs[4]  = {x0, x0+1, x0,   x0+1};
        int   ys[4]  = {y0, y0,   y0+1, y0+1};
        float ws4[4] = {wq*(1.f-wx)*(1.f-wy), wq*wx*(1.f-wy), wq*(1.f-wx)*wy, wq*wx*wy};
        #pragma unroll
        for (int ci = 0; ci < 4; ci++){
            int xi = xs[ci], yi = ys[ci];
            if ((unsigned)xi < WWF && (unsigned)yi < HHF){
                const unsigned short* vp =
                    value + ((size_t)b*HWF + yi*WWF + xi)*256 + h*32 + slice*8;
                float v[8]; load_bf16x8(vp, v);
                float wgt = ws4[ci];
                #pragma unroll
                for (int i = 0; i < 8; i++) acc[i] += wgt * v[i];
            }
        }
    }
    store_bf16x8(g2 + (size_t)m*256 + h*32 + slice*8, acc);
}

// ================== K3: final — out = [g2 | bf16(qe)] @ WgT2^T + bconst =============
__global__ __launch_bounds__(256) void final2_kernel(
    const unsigned short* __restrict__ g2,     // [4096][256] bf16
    const float* __restrict__ qe,              // [4096][256] f32
    const unsigned short* __restrict__ WgT2,   // [256 n][512 k] bf16
    const float* __restrict__ bconst,          // [256]
    float* __restrict__ out)                   // [4096][256]
{
    __shared__ __align__(16) unsigned short As[16*512];   // 16 KB, swizzled
    const int m0  = blockIdx.x * 16;
    const int tid = threadIdx.x;
    const int w = tid >> 6, l = tid & 63, lrow = l & 15, lk = l >> 4;

    {   // stage A: k<256 from g2, k>=256 from qe (cvt f32->bf16)
        int row = tid >> 4, lane16 = tid & 15;
        const unsigned short* gp = g2 + (size_t)(m0 + row)*256;
        const float* qp = qe + (size_t)(m0 + row)*256;
        char* dst = (char*)(As + row*512);
        #pragma unroll
        for (int s = 0; s < 2; s++){
            int kb = lane16*32 + s*16;
            int4 v = *reinterpret_cast<const int4*>((const char*)gp + kb);
            *reinterpret_cast<int4*>(dst + (kb ^ ((row & 7) << 4))) = v;
        }
        #pragma unroll
        for (int s = 0; s < 2; s++){
            union { unsigned short u[8]; int4 t; } cu;
            #pragma unroll
            for (int uu = 0; uu < 8; uu++) cu.u[uu] = f2bf(qp[lane16*16 + s*8 + uu]);
            int kb = 512 + lane16*32 + s*16;
            *reinterpret_cast<int4*>(dst + (kb ^ ((row & 7) << 4))) = cu.t;
        }
    }
    __syncthreads();

    f32x4 acc0 = {0.f,0.f,0.f,0.f};
    f32x4 acc1 = {0.f,0.f,0.f,0.f};
    f32x4 acc2 = {0.f,0.f,0.f,0.f};
    f32x4 acc3 = {0.f,0.f,0.f,0.f};
    const unsigned short* Bp = WgT2 + (size_t)(w*64 + lrow)*512 + lk*8;
    const char* Ab = (const char*)(As + lrow*512);
    const int asw = (lrow & 7) << 4;

    #pragma unroll
    for (int k0 = 0; k0 < 512; k0 += 32){
        bf16x8 a  = *reinterpret_cast<const bf16x8*>(Ab + (((k0 + lk*8)*2) ^ asw));
        bf16x8 b0 = *reinterpret_cast<const bf16x8*>(Bp + k0);
        bf16x8 b1 = *reinterpret_cast<const bf16x8*>(Bp + 16*512 + k0);
        bf16x8 b2 = *reinterpret_cast<const bf16x8*>(Bp + 32*512 + k0);
        bf16x8 b3 = *reinterpret_cast<const bf16x8*>(Bp + 48*512 + k0);
        acc0 = __builtin_amdgcn_mfma_f32_16x16x32_bf16(a, b0, acc0, 0, 0, 0);
        acc1 = __builtin_amdgcn_mfma_f32_16x16x32_bf16(a, b1, acc1, 0, 0, 0);
        acc2 = __builtin_amdgcn_mfma_f32_16x16x32_bf16(a, b2, acc2, 0, 0, 0);
        acc3 = __builtin_amdgcn_mfma_f32_16x16x32_bf16(a, b3, acc3, 0, 0, 0);
    }

    const f32x4 accs[4] = {acc0, acc1, acc2, acc3};
    #pragma unroll
    for (int nt = 0; nt < 4; nt++){
        int c = w*64 + nt*16 + lrow;
        float bcv = bconst[c];
        #pragma unroll
        for (int i = 0; i < 4; i++){
            int r = m0 + lk*4 + i;
            out[(size_t)r*256 + c] = accs[nt][i] + bcv;
        }
    }
}

extern "C" void kernel_launch(void* const* d_in, const int* in_sizes, int n_in,
                              void* d_out, int out_size, void* d_ws, size_t ws_size,
                              hipStream_t stream)
{
    (void)in_sizes; (void)n_in; (void)out_size; (void)ws_size;
    float* out = (float*)d_out;
    char*  ws  = (char*)d_ws;

    const size_t OF_CO   = 0;                                  // coords 4096*8*64B
    const size_t OF_WGT2 = OF_CO   + (size_t)4096*8*64;        //  2,097,152
    const size_t OF_BC   = OF_WGT2 + (size_t)256*512*2;        //  2,359,296
    const size_t OF_WVT  = OF_BC   + 1024;                     //  2,360,320
    const size_t OF_G2   = OF_WVT  + (size_t)256*256*2;        //  2,491,392
    const size_t OF_VAL  = OF_G2   + (size_t)4096*256*2;       //  4,588,544
    // NEED = OF_VAL + 4*40000*256*2 = 86,508,544 (ws proven >= 102.1 MB in R2-R4)

    float*          coords = (float*)(ws + OF_CO);
    unsigned short* WgT2   = (unsigned short*)(ws + OF_WGT2);
    float*          bconst = (float*)(ws + OF_BC);
    unsigned short* WvalT  = (unsigned short*)(ws + OF_WVT);
    unsigned short* g2     = (unsigned short*)(ws + OF_G2);
    unsigned short* value  = (unsigned short*)(ws + OF_VAL);

    const float* qe    = (const float*)d_in[0];
    const float* ctrl  = (const float*)d_in[1];
    const float* bev   = (const float*)d_in[2];
    const float* pc    = (const float*)d_in[4];
    const float* Wq    = (const float*)d_in[5];
    const float* bq    = (const float*)d_in[6];
    const float* Wval  = (const float*)d_in[7];
    const float* bval  = (const float*)d_in[8];
    const float* Woff  = (const float*)d_in[9];
    const float* boff  = (const float*)d_in[10];
    const float* Wattn = (const float*)d_in[11];
    const float* battn = (const float*)d_in[12];
    const float* Wdo   = (const float*)d_in[13];
    const float* bdo   = (const float*)d_in[14];
    const float* Wout  = (const float*)d_in[15];
    const float* bout  = (const float*)d_in[16];

    // K0: weight-only prep (WgT2, bconst, WvalT)
    prep_kernel<<<37, 256, 0, stream>>>(Wq, bq, Wval, Wdo, bdo, Wout, bout,
                                        WgT2, bconst, WvalT);
    // K1: value precompute (512-B granular reads) + self-contained oa
    valoa_kernel<<<1316, 256, 0, stream>>>(bev, WvalT, bval, qe, ctrl, pc,
                                           Wq, bq, Woff, boff, Wattn, battn,
                                           value, coords);
    // K2: gather (1KB per (m,h))
    gather2_kernel<<<512, 256, 0, stream>>>(value, coords, g2);
    // K3: fused back-end GEMM
    final2_kernel<<<256, 256, 0, stream>>>(g2, qe, WgT2, bconst, out);
}